// Round 4
// baseline (744.029 us; speedup 1.0000x reference)
//
#include <hip/hip_runtime.h>
#include <stdint.h>

#define WIN 14
#define HW 196
#define NH 12
#define HIDDEN 768
#define BH 3072
#define MTOT 50176
#define KDIM 768

typedef __bf16 bf16x8 __attribute__((ext_vector_type(8)));
typedef float f32x4 __attribute__((ext_vector_type(4)));

__device__ __forceinline__ float bf2f(uint16_t u) {
  union { uint32_t i; float f; } v; v.i = ((uint32_t)u) << 16; return v.f;
}
__device__ __forceinline__ uint16_t f2bf(float f) {
  uint32_t u = __float_as_uint(f);
  uint32_t r = u + 0x7FFFu + ((u >> 16) & 1u);
  return (uint16_t)(r >> 16);
}
__device__ __forceinline__ uint32_t pack2bf(float a, float b) {
  return (uint32_t)f2bf(a) | ((uint32_t)f2bf(b) << 16);
}
__device__ __forceinline__ f32x4 mfma16(bf16x8 a, bf16x8 b, f32x4 c) {
  return __builtin_amdgcn_mfma_f32_16x16x32_bf16(a, b, c, 0, 0, 0);
}
__device__ __forceinline__ f32x4 f4zero() { f32x4 z = {0.f, 0.f, 0.f, 0.f}; return z; }

__device__ __forceinline__ void async16(const void* g, void* l) {
#if __has_builtin(__builtin_amdgcn_global_load_lds)
  __builtin_amdgcn_global_load_lds((__attribute__((address_space(1))) void*)g,
                                   (__attribute__((address_space(3))) void*)l, 16, 0, 0);
#else
  *(uint4*)l = *(const uint4*)g;
#endif
}

// ---------------- fused prep: 3x fp32->bf16 convert + rel-pos table ----------------
// blocks [0,4096): hidden; [4096,5120): qkv_w; [5120,5696): proj_w; [5696,5712): Rt.
__global__ __launch_bounds__(256) void prep(const float* __restrict__ hidden,
                                            const float* __restrict__ qkv_w,
                                            const float* __restrict__ proj_w,
                                            const float* __restrict__ rh,
                                            const float* __restrict__ rw,
                                            uint16_t* __restrict__ Xb,
                                            uint16_t* __restrict__ wqkvb,
                                            uint16_t* __restrict__ wprjb,
                                            uint16_t* __restrict__ Rt) {
  const int blk = blockIdx.x;
  if (blk < 4096) {
    const int n4 = (MTOT * HIDDEN) / 4;
    int i = blk * 256 + threadIdx.x;
    for (; i < n4; i += 4096 * 256) {
      float4 v = ((const float4*)hidden)[i];
      ushort4 o;
      o.x = f2bf(v.x); o.y = f2bf(v.y); o.z = f2bf(v.z); o.w = f2bf(v.w);
      ((ushort4*)Xb)[i] = o;
    }
  } else if (blk < 5120) {
    const int n4 = (3 * HIDDEN * HIDDEN) / 4;
    int i = (blk - 4096) * 256 + threadIdx.x;
    for (; i < n4; i += 1024 * 256) {
      float4 v = ((const float4*)qkv_w)[i];
      ushort4 o;
      o.x = f2bf(v.x); o.y = f2bf(v.y); o.z = f2bf(v.z); o.w = f2bf(v.w);
      ((ushort4*)wqkvb)[i] = o;
    }
  } else if (blk < 5696) {
    const int n4 = (HIDDEN * HIDDEN) / 4;
    int i = (blk - 5120) * 256 + threadIdx.x;
    if (i < n4) {
      float4 v = ((const float4*)proj_w)[i];
      ushort4 o;
      o.x = f2bf(v.x); o.y = f2bf(v.y); o.z = f2bf(v.z); o.w = f2bf(v.w);
      ((ushort4*)wprjb)[i] = o;
    }
  } else {
    const int i = (blk - 5696) * 256 + threadIdx.x;
    if (i < 4096) {
      const int r = i >> 6, c = i & 63;
      float v = 0.f;
      if (r < 27) v = rh[r * 64 + c] * 8.f;
      else if (r >= 32 && r < 59) v = rw[(r - 32) * 64 + c] * 8.f;
      Rt[i] = f2bf(v);
    }
  }
}

// ---------------- GEMM: C[m][n] = sum_k A[m][k]*B[n][k] (+bias), bf16 in, K=768 ----
// PERSISTENT: grid = 256 blocks (1/CU), each owns a contiguous chunk of 6-7 tiles
// (row-major, n-fastest -> chunk shares A-panels). 256x256 tile, BK=64, 8 waves,
// 8-phase double-barrier schedule (T3+T4+T5) with the stage targets forming a
// virtual continuous K-stream ACROSS tile boundaries: at j=5, S+2/S+3 land in the
// next tile's K-tiles 0/1 (12 K-tiles/tile keeps slot parity). vmcnt(4) ledger is
// identical across boundaries; vmcnt(0) only at the final tile's last iteration.
// MFMA operands SWAPPED (acc = C^T): lane's 4 rg = 4 consecutive n -> vectorized
// epilogue (ushort4 / float4 stores), bias as float4.
template <int EPI>
__global__ __launch_bounds__(512, 2) void gemm_bt(const uint16_t* __restrict__ A,
                                                  const uint16_t* __restrict__ B,
                                                  const float* __restrict__ bias,
                                                  void* __restrict__ outp) {
  constexpr int NBX = (EPI == 0) ? 9 : 3;
  constexpr int NTILES = (EPI == 0) ? 1764 : 588;
  __shared__ __align__(16) uint16_t lds[8 * 8192];  // 128 KB

  const int tid = threadIdx.x;
  const int p = blockIdx.x;  // 0..255
  constexpr int QT = NTILES >> 8, RT = NTILES & 255;
  const int start = (p < RT) ? p * (QT + 1) : RT * (QT + 1) + (p - RT) * QT;
  const int cnt = (p < RT) ? QT + 1 : QT;

  const int lane = tid & 63;
  const int wave = tid >> 6;
  const int l15 = lane & 15, quad = lane >> 4;
  const int wr = wave >> 2, wc = wave & 3;
  const int wm = wr * 128, wn = wc * 64;

  // per-thread staging geometry (loop-invariant)
  const int st_r = tid >> 3;
  const int st_c = (tid & 7) ^ (st_r & 7);

  auto STAGE = [&](const uint16_t* src, int rowbase, int kt, int slot) {
#pragma unroll
    for (int jj = 0; jj < 2; ++jj) {
      const int row = rowbase + st_r + jj * 64;
      async16(src + (size_t)row * KDIM + kt * 64 + st_c * 8,
              (uint8_t*)(lds + slot * 8192) + tid * 16 + jj * 8192);
    }
  };

  // loop-invariant fragment-read swizzle offsets (rA&7 == rB&7 == l15&7)
  const int sw0 = (quad ^ (l15 & 7)) * 8;
  const int sw1 = ((4 + quad) ^ (l15 & 7)) * 8;
  const uint16_t* Aslot = lds + (size_t)wr * 8192;
  const uint16_t* Bslot = lds + (size_t)(4 + (wc >> 1)) * 8192;
  const int rBb = (wc & 1) * 64;

  // tile coordinates: cur + next
  int tm = ((start) / NBX) * 256, tn = ((start) % NBX) * 256;
  int tmn = tm, tnn = tn;
  if (cnt > 1) {
    tmn = ((start + 1) / NBX) * 256;
    tnn = ((start + 1) % NBX) * 256;
  }

  // prologue: first tile K-tiles 0 (A slots 0,1; B slots 4,5) and 1 (B slots 6,7)
  STAGE(A, tm, 0, 0);
  STAGE(A, tm + 128, 0, 1);
  STAGE(B, tn, 0, 4);
  STAGE(B, tn + 128, 0, 5);
  STAGE(B, tn, 1, 6);
  STAGE(B, tn + 128, 1, 7);
  asm volatile("s_waitcnt vmcnt(4)" ::: "memory");
  __builtin_amdgcn_s_barrier();

#pragma unroll 1
  for (int tv = 0; tv < cnt; ++tv) {
    f32x4 acc[8][4];
#pragma unroll
    for (int mi = 0; mi < 8; mi++)
#pragma unroll
      for (int ni = 0; ni < 4; ni++) acc[mi][ni] = f4zero();

    const bool lastT = (tv == cnt - 1);
#pragma unroll 1
    for (int j = 0; j < 6; ++j) {
      const int S = 2 * j;
      const bool cross = (j == 5);           // S+2==12, S+3==13 -> next tile
      const bool ok2 = !cross || !lastT;
      const bool ok3 = !cross || !lastT;
      const int k2 = cross ? 0 : S + 2;
      const int k3 = cross ? 1 : S + 3;
      const int am2 = cross ? tmn : tm;
      const int bn2 = cross ? tnn : tn;
      const int bn3 = cross ? tnn : tn;
#pragma unroll
      for (int pb = 0; pb < 2; ++pb) {
        bf16x8 bfr[4][2];
#pragma unroll
        for (int q = 0; q < 4; ++q) {
          // ---- ds reads for this phase
          if (q == 0) {
#pragma unroll
            for (int ni = 0; ni < 4; ++ni) {
              const int rB = rBb + ni * 16 + l15;
              const uint16_t* bp = Bslot + pb * 16384 + rB * 64;
              bfr[ni][0] = *(const bf16x8*)(bp + sw0);
              bfr[ni][1] = *(const bf16x8*)(bp + sw1);
            }
          }
          bf16x8 af[2][2];
#pragma unroll
          for (int m2 = 0; m2 < 2; ++m2) {
            const int rA = (q * 2 + m2) * 16 + l15;
            const uint16_t* ap = Aslot + pb * 16384 + rA * 64;
            af[m2][0] = *(const bf16x8*)(ap + sw0);
            af[m2][1] = *(const bf16x8*)(ap + sw1);
          }
          // ---- stage one half-tile per schedule
          if (pb == 0) {
            if (q == 0) STAGE(A, tm, S + 1, 2);
            else if (q == 1) STAGE(A, tm + 128, S + 1, 3);
            else if (q == 2) { if (ok2) STAGE(B, bn2, k2, 4); }
            else { if (ok2) STAGE(B, bn2 + 128, k2, 5); }
          } else {
            if (q == 0) { if (ok2) STAGE(A, am2, k2, 0); }
            else if (q == 1) { if (ok2) STAGE(A, am2 + 128, k2, 1); }
            else if (q == 2) { if (ok3) STAGE(B, bn3, k3, 6); }
            else { if (ok3) STAGE(B, bn3 + 128, k3, 7); }
          }
          __builtin_amdgcn_s_barrier();
          asm volatile("s_waitcnt lgkmcnt(0)" ::: "memory");
          __builtin_amdgcn_sched_barrier(0);
          __builtin_amdgcn_s_setprio(1);
#pragma unroll
          for (int kk = 0; kk < 2; ++kk)
#pragma unroll
            for (int m2 = 0; m2 < 2; ++m2)
#pragma unroll
              for (int ni = 0; ni < 4; ++ni)
                acc[q * 2 + m2][ni] = mfma16(bfr[ni][kk], af[m2][kk], acc[q * 2 + m2][ni]);
          __builtin_amdgcn_s_setprio(0);
          if (q == 3) {
            const bool keep = (pb == 0) ? ok2 : ok3;
            if (keep) asm volatile("s_waitcnt vmcnt(4)" ::: "memory");
            else asm volatile("s_waitcnt vmcnt(0)" ::: "memory");
          }
          __builtin_amdgcn_s_barrier();
        }
      }
    }

    // ---- epilogue (acc is C^T: row quad*4+rg = n, col l15 = m)
#pragma unroll
    for (int ni = 0; ni < 4; ++ni) {
      const int n0 = tn + wn + ni * 16 + quad * 4;
      const float4 bb = *(const float4*)(bias + n0);
      if (EPI == 0) {
        const int which = n0 / HIDDEN;
        const int rem = n0 - which * HIDDEN;
        const int head = rem >> 6, d0 = rem & 63;
        const float sc = (which == 0) ? 0.125f : 1.f;
        const size_t cA = (size_t)which * BH * HW * 64 + (size_t)head * HW * 64 + d0;
#pragma unroll
        for (int mi = 0; mi < 8; ++mi) {
          const int m = tm + wm + mi * 16 + l15;
          const int b_ = m / HW;
          const int s_ = m - b_ * HW;
          ushort4 o;
          o.x = f2bf((acc[mi][ni][0] + bb.x) * sc);
          o.y = f2bf((acc[mi][ni][1] + bb.y) * sc);
          o.z = f2bf((acc[mi][ni][2] + bb.z) * sc);
          o.w = f2bf((acc[mi][ni][3] + bb.w) * sc);
          *(ushort4*)((uint16_t*)outp + cA + ((size_t)b_ * NH) * HW * 64 + (size_t)s_ * 64) = o;
        }
      } else {
#pragma unroll
        for (int mi = 0; mi < 8; ++mi) {
          const int m = tm + wm + mi * 16 + l15;
          float4 o;
          o.x = acc[mi][ni][0] + bb.x;
          o.y = acc[mi][ni][1] + bb.y;
          o.z = acc[mi][ni][2] + bb.z;
          o.w = acc[mi][ni][3] + bb.w;
          *(float4*)((float*)outp + (size_t)m * HIDDEN + n0) = o;
        }
      }
    }

    // ---- advance tile coords (next-next computed for staging lookahead)
    tm = tmn; tn = tnn;
    const int vn2 = start + tv + 2;
    if (tv + 2 < cnt) {
      tmn = (vn2 / NBX) * 256;
      tnn = (vn2 % NBX) * 256;
    }
  }
}

// ---------------- fused attention (swapped-operand form) ----------------
__global__ __launch_bounds__(256, 4) void attn_kernel(const uint16_t* __restrict__ qkv,
                                                      const uint16_t* __restrict__ Rt,
                                                      uint16_t* __restrict__ aout) {
  __shared__ __align__(16) uint8_t smem[37376];
  uint16_t* Ks = (uint16_t*)smem;              // [208][64] chunk-swizzled
  uint16_t* Vt = (uint16_t*)smem;              // [64][224] kappa-order, chunk-swizzled
  uint16_t* Ts = (uint16_t*)(smem + 28672);    // [64][68]: T^T[r][q_local]

  const int wgid = blockIdx.x;                 // 0..12287
  const int jsw = (wgid & 7) * 1536 + (wgid >> 3);  // XCD swizzle (12288 % 8 == 0)
  const int qt = jsw & 3;
  const int bh = jsw >> 2;
  const int q0 = qt * 64;
  const int tid = threadIdx.x;
  const int wave = tid >> 6, lane = tid & 63;
  const int l15 = lane & 15, quad = lane >> 4;

  const uint16_t* qg = qkv + (size_t)bh * HW * 64;
  const uint16_t* kg = qkv + ((size_t)BH + bh) * HW * 64;
  const uint16_t* vg = qkv + ((size_t)2 * BH + bh) * HW * 64;

  // ---- stage K -> Ks, chunk-swizzled: (r, chunk c) at r*64 + (c^(r&7))*8
#pragma unroll
  for (int i = 0; i < 7; i++) {
    const int c = tid + i * 256;
    if (c < 1568) {
      const int r = c >> 3, ch = c & 7;
      uint4 v = *(const uint4*)(kg + (size_t)r * 64 + ch * 8);
      *(uint4*)(Ks + r * 64 + ((ch ^ (r & 7)) * 8)) = v;
    }
  }

  // ---- Q fragment straight from global (b-operand: row=l15, chunk=quad)
  const int qrow = q0 + wave * 16 + l15;       // this lane's q row
  const int qr = (qrow < HW) ? qrow : (HW - 1);
  bf16x8 qb0 = *(const bf16x8*)(qg + (size_t)qr * 64 + quad * 8);
  bf16x8 qb1 = *(const bf16x8*)(qg + (size_t)qr * 64 + 32 + quad * 8);

  // ---- T^T = Rt * Q^T : lane holds T^T[r = t*16+quad*4+rg][q=l15]; spill to Ts
  {
    f32x4 racc[4];
#pragma unroll
    for (int t = 0; t < 4; t++) racc[t] = f4zero();
    __builtin_amdgcn_s_setprio(1);
#pragma unroll
    for (int t = 0; t < 4; t++) {
      bf16x8 r0 = *(const bf16x8*)(Rt + (t * 16 + l15) * 64 + quad * 8);
      bf16x8 r1 = *(const bf16x8*)(Rt + (t * 16 + l15) * 64 + 32 + quad * 8);
      racc[t] = mfma16(r0, qb0, racc[t]);
      racc[t] = mfma16(r1, qb1, racc[t]);
    }
    __builtin_amdgcn_s_setprio(0);
#pragma unroll
    for (int t = 0; t < 4; t++)
#pragma unroll
      for (int rg = 0; rg < 4; rg++)
        Ts[(t * 16 + quad * 4 + rg) * 68 + wave * 16 + l15] = f2bf(racc[t][rg]);
  }

  __syncthreads();  // Ks staged (Ts writes also ordered before all later reads)

  // ---- prefetch V into registers (latency hidden under S-phase MFMAs)
  uint4 vreg[7];
#pragma unroll
  for (int i = 0; i < 7; i++) {
    const int c = tid + i * 256;
    vreg[i] = (c < 1568) ? *(const uint4*)(vg + (size_t)c * 8) : make_uint4(0u, 0u, 0u, 0u);
  }

  // ---- S^T = K * Q^T : lane holds S[j = t*16+quad*4+rg][its own q]
  f32x4 sacc[13];
#pragma unroll
  for (int t = 0; t < 13; t++) sacc[t] = f4zero();
  {
    const int sw0 = (quad ^ (l15 & 7)) * 8;
    const int sw1 = ((quad + 4) ^ (l15 & 7)) * 8;
    __builtin_amdgcn_s_setprio(1);
#pragma unroll
    for (int t = 0; t < 13; t++) {
      const uint16_t* kr = Ks + (t * 16 + l15) * 64;
      bf16x8 a0 = *(const bf16x8*)(kr + sw0);
      bf16x8 a1 = *(const bf16x8*)(kr + sw1);
      sacc[t] = mfma16(a0, qb0, sacc[t]);
      sacc[t] = mfma16(a1, qb1, sacc[t]);
    }
    __builtin_amdgcn_s_setprio(0);
  }

  __syncthreads();  // all waves done reading Ks; V loads drained before overlay

  // ---- zero the kappa-tail columns [196,224) of Vt (one store per thread)
  {
    const int d = tid & 63, wv = tid >> 6;
    if (wv == 0) *(uint2*)(Vt + d * 224 + 196) = make_uint2(0u, 0u);
    else *(uint4*)(Vt + d * 224 + 200 + (wv - 1) * 8) = make_uint4(0u, 0u, 0u, 0u);
  }

  // ---- V^T into Vt in kappa-order, swizzled; writes are bank-conflict-free
  // kappa(j): j = t*16 + qj*4 + rg  ->  (t>>1)*32 + qj*8 + (t&1)*4 + rg
#pragma unroll
  for (int i = 0; i < 7; i++) {
    const int c = tid + i * 256;
    if (c < 1568) {
      const int jj = c >> 3;
      const int dp = c & 7;               // d block: rows dp*8 .. dp*8+7
      const int tt = jj >> 4;
      const int kap = (tt >> 1) * 32 + ((jj >> 2) & 3) * 8 + (tt & 1) * 4 + (jj & 3);
      const int cj = kap >> 3;
      const int chs = (cj < 24) ? ((cj & 24) | ((cj & 7) ^ dp)) : cj;
      uint16_t* dst = Vt + dp * 8 * 224 + chs * 8 + (kap & 7);
      const uint16_t* pe = (const uint16_t*)&vreg[i];
#pragma unroll
      for (int e = 0; e < 8; e++) dst[e * 224] = pe[e];
    }
  }

  // ---- softmax fully in registers (row = lane's own q); bias from Ts
  uint32_t P2[13][2];
  {
    const int hq = (qr * 586) >> 13;      // qr / 14
    const int wq = qr - hq * 14;
    const uint16_t* Tb = Ts + wave * 16 + l15;   // column base, rows stride 68
    const int c0 = (hq + 13) * 68;
    const int c1 = (wq + 45) * 68;
    float mx0 = -1e30f, mx1 = -1e30f, mx2 = -1e30f, mx3 = -1e30f;
#pragma unroll
    for (int t = 0; t < 13; t++) {
#pragma unroll
      for (int rg = 0; rg < 4; rg++) {
        const int j = t * 16 + quad * 4 + rg;
        const int kh = (j * 586) >> 13;   // j / 14 (valid for j <= 195)
        const int kw = j - kh * 14;
        const float b = bf2f(Tb[c0 - kh * 68]) + bf2f(Tb[c1 - kw * 68]);
        float s = sacc[t][rg] + b;
        s = (j < HW) ? s : -1e30f;
        sacc[t][rg] = s;
        if (rg == 0) mx0 = fmaxf(mx0, s);
        else if (rg == 1) mx1 = fmaxf(mx1, s);
        else if (rg == 2) mx2 = fmaxf(mx2, s);
        else mx3 = fmaxf(mx3, s);
      }
    }
    float mx = fmaxf(fmaxf(mx0, mx1), fmaxf(mx2, mx3));
    mx = fmaxf(mx, __shfl_xor(mx, 16, 64));
    mx = fmaxf(mx, __shfl_xor(mx, 32, 64));
    float s0 = 0.f, s1 = 0.f, s2 = 0.f, s3 = 0.f;
#pragma unroll
    for (int t = 0; t < 13; t++) {
#pragma unroll
      for (int rg = 0; rg < 4; rg++) {
        const float p = __expf(sacc[t][rg] - mx);
        sacc[t][rg] = p;
        if (rg == 0) s0 += p;
        else if (rg == 1) s1 += p;
        else if (rg == 2) s2 += p;
        else s3 += p;
      }
    }
    float sum = (s0 + s1) + (s2 + s3);
    sum += __shfl_xor(sum, 16, 64);
    sum += __shfl_xor(sum, 32, 64);
    const float inv = 1.f / sum;
#pragma unroll
    for (int t = 0; t < 13; t++) {
      P2[t][0] = pack2bf(sacc[t][0] * inv, sacc[t][1] * inv);
      P2[t][1] = pack2bf(sacc[t][2] * inv, sacc[t][3] * inv);
    }
  }

  __syncthreads();  // all Vt writes visible before PV reads

  // ---- O = P*V : A-fragment is the lane's own P2 registers (kappa order)
  f32x4 oacc[4];
#pragma unroll
  for (int nt = 0; nt < 4; nt++) oacc[nt] = f4zero();
  {
    __builtin_amdgcn_s_setprio(1);
#pragma unroll
    for (int ks = 0; ks < 7; ks++) {
      uint4 aw;
      aw.x = P2[2 * ks][0];
      aw.y = P2[2 * ks][1];
      aw.z = (ks < 6) ? P2[2 * ks + 1][0] : 0u;
      aw.w = (ks < 6) ? P2[2 * ks + 1][1] : 0u;
      const bf16x8 af = __builtin_bit_cast(bf16x8, aw);
      const int cb = ks * 4 + quad;       // kappa chunk
#pragma unroll
      for (int nt = 0; nt < 4; nt++) {
        const int d = nt * 16 + l15;
        const int p = (d >> 3) & 7;
        const int chs = (cb < 24) ? ((cb & 24) | ((cb & 7) ^ p)) : cb;
        bf16x8 bv = *(const bf16x8*)(Vt + d * 224 + chs * 8);
        oacc[nt] = mfma16(af, bv, oacc[nt]);
      }
    }
    __builtin_amdgcn_s_setprio(0);
  }

  const int b = bh / NH, head = bh - b * NH;
#pragma unroll
  for (int nt = 0; nt < 4; nt++) {
#pragma unroll
    for (int rg = 0; rg < 4; rg++) {
      const int qro = q0 + wave * 16 + quad * 4 + rg;
      if (qro < HW) {
        const int d = nt * 16 + l15;
        aout[((size_t)b * HW + qro) * HIDDEN + head * 64 + d] = f2bf(oacc[nt][rg]);
      }
    }
  }
}

extern "C" void kernel_launch(void* const* d_in, const int* in_sizes, int n_in,
                              void* d_out, int out_size, void* d_ws, size_t ws_size,
                              hipStream_t stream) {
  const float* hidden = (const float*)d_in[0];
  const float* qkv_w = (const float*)d_in[1];
  const float* qkv_b = (const float*)d_in[2];
  const float* proj_w = (const float*)d_in[3];
  const float* proj_b = (const float*)d_in[4];
  const float* rel_h = (const float*)d_in[5];
  const float* rel_w = (const float*)d_in[6];

  uint8_t* ws = (uint8_t*)d_ws;
  uint16_t* Xb = (uint16_t*)(ws);                  // 77,070,336 B; reused as attn_out
  uint16_t* qkvb = (uint16_t*)(ws + 77070336);     // 231,211,008 B: [3][3072][196][64] bf16
  uint16_t* Rt = (uint16_t*)(ws + 308281344);      // 8,192 B: [64][64] bf16 rel table
  uint16_t* wqkvb = (uint16_t*)(ws + 308289536);   // 3,538,944 B
  uint16_t* wprjb = (uint16_t*)(ws + 311828480);   // 1,179,648 B

  prep<<<5712, 256, 0, stream>>>(hidden, qkv_w, proj_w, rel_h, rel_w,
                                 Xb, wqkvb, wprjb, Rt);

  gemm_bt<0><<<256, 512, 0, stream>>>(Xb, wqkvb, qkv_b, (void*)qkvb);
  attn_kernel<<<dim3(12288), 256, 0, stream>>>(qkvb, Rt, Xb);
  gemm_bt<1><<<256, 512, 0, stream>>>(Xb, wprjb, proj_b, d_out);
}

// Round 5
// 730.699 us; speedup vs baseline: 1.0182x; 1.0182x over previous
//
#include <hip/hip_runtime.h>
#include <stdint.h>

#define WIN 14
#define HW 196
#define NH 12
#define HIDDEN 768
#define BH 3072
#define MTOT 50176
#define KDIM 768

typedef __bf16 bf16x8 __attribute__((ext_vector_type(8)));
typedef float f32x4 __attribute__((ext_vector_type(4)));

__device__ __forceinline__ float bf2f(uint16_t u) {
  union { uint32_t i; float f; } v; v.i = ((uint32_t)u) << 16; return v.f;
}
__device__ __forceinline__ uint16_t f2bf(float f) {
  uint32_t u = __float_as_uint(f);
  uint32_t r = u + 0x7FFFu + ((u >> 16) & 1u);
  return (uint16_t)(r >> 16);
}
__device__ __forceinline__ uint32_t pack2bf(float a, float b) {
  return (uint32_t)f2bf(a) | ((uint32_t)f2bf(b) << 16);
}
__device__ __forceinline__ f32x4 mfma16(bf16x8 a, bf16x8 b, f32x4 c) {
  return __builtin_amdgcn_mfma_f32_16x16x32_bf16(a, b, c, 0, 0, 0);
}
__device__ __forceinline__ f32x4 f4zero() { f32x4 z = {0.f, 0.f, 0.f, 0.f}; return z; }

__device__ __forceinline__ void async16(const void* g, void* l) {
#if __has_builtin(__builtin_amdgcn_global_load_lds)
  __builtin_amdgcn_global_load_lds((__attribute__((address_space(1))) void*)g,
                                   (__attribute__((address_space(3))) void*)l, 16, 0, 0);
#else
  *(uint4*)l = *(const uint4*)g;
#endif
}

// ---------------- fused prep: 3x fp32->bf16 convert + rel-pos table ----------------
// blocks [0,4096): hidden; [4096,5120): qkv_w; [5120,5696): proj_w; [5696,5712): Rt.
__global__ __launch_bounds__(256) void prep(const float* __restrict__ hidden,
                                            const float* __restrict__ qkv_w,
                                            const float* __restrict__ proj_w,
                                            const float* __restrict__ rh,
                                            const float* __restrict__ rw,
                                            uint16_t* __restrict__ Xb,
                                            uint16_t* __restrict__ wqkvb,
                                            uint16_t* __restrict__ wprjb,
                                            uint16_t* __restrict__ Rt) {
  const int blk = blockIdx.x;
  if (blk < 4096) {
    const int n4 = (MTOT * HIDDEN) / 4;
    int i = blk * 256 + threadIdx.x;
    for (; i < n4; i += 4096 * 256) {
      float4 v = ((const float4*)hidden)[i];
      ushort4 o;
      o.x = f2bf(v.x); o.y = f2bf(v.y); o.z = f2bf(v.z); o.w = f2bf(v.w);
      ((ushort4*)Xb)[i] = o;
    }
  } else if (blk < 5120) {
    const int n4 = (3 * HIDDEN * HIDDEN) / 4;
    int i = (blk - 4096) * 256 + threadIdx.x;
    for (; i < n4; i += 1024 * 256) {
      float4 v = ((const float4*)qkv_w)[i];
      ushort4 o;
      o.x = f2bf(v.x); o.y = f2bf(v.y); o.z = f2bf(v.z); o.w = f2bf(v.w);
      ((ushort4*)wqkvb)[i] = o;
    }
  } else if (blk < 5696) {
    const int n4 = (HIDDEN * HIDDEN) / 4;
    int i = (blk - 5120) * 256 + threadIdx.x;
    if (i < n4) {
      float4 v = ((const float4*)proj_w)[i];
      ushort4 o;
      o.x = f2bf(v.x); o.y = f2bf(v.y); o.z = f2bf(v.z); o.w = f2bf(v.w);
      ((ushort4*)wprjb)[i] = o;
    }
  } else {
    const int i = (blk - 5696) * 256 + threadIdx.x;
    if (i < 4096) {
      const int r = i >> 6, c = i & 63;
      float v = 0.f;
      if (r < 27) v = rh[r * 64 + c] * 8.f;
      else if (r >= 32 && r < 59) v = rw[(r - 32) * 64 + c] * 8.f;
      Rt[i] = f2bf(v);
    }
  }
}

// ---------------- GEMM: C[m][n] = sum_k A[m][k]*B[n][k] (+bias), bf16 in, K=768 ----
// PERSISTENT, XCD-LOCAL: tiles split into 8 contiguous per-XCD slabs (disjoint
// m-ranges); within XCD x (blocks p%8==x), the 32 blocks take tiles
// base_x + loc + i*32 -> at any instant an XCD's 32 blocks work on 32 CONTIGUOUS
// tile ids (~3.5 A-panels ~ 1.4 MB), which fits the 4 MB per-XCD L2; each A-panel
// is fetched from HBM once. 256x256 tile, BK=64, 8 waves, 8-phase double-barrier
// schedule (T3+T4+T5); stage targets form a virtual continuous K-stream across
// tile boundaries (12 K-tiles/tile keeps slot parity; vmcnt(4) ledger identical
// across boundaries; vmcnt(0) only at the final tile's last iteration).
// MFMA operands SWAPPED (acc = C^T): lane's 4 rg = 4 consecutive n -> vectorized
// epilogue (ushort4 / float4 stores), bias as float4.
template <int EPI>
__global__ __launch_bounds__(512, 2) void gemm_bt(const uint16_t* __restrict__ A,
                                                  const uint16_t* __restrict__ B,
                                                  const float* __restrict__ bias,
                                                  void* __restrict__ outp) {
  constexpr int NBX = (EPI == 0) ? 9 : 3;
  constexpr int NTILES = (EPI == 0) ? 1764 : 588;
  constexpr int QX = NTILES / 8, RX = NTILES % 8;
  __shared__ __align__(16) uint16_t lds[8 * 8192];  // 128 KB

  const int tid = threadIdx.x;
  const int p = blockIdx.x;                  // 0..255
  const int xcd = p & 7, loc = p >> 3;       // hw round-robin: block p -> XCD p%8
  const int base_x = xcd * QX + (xcd < RX ? xcd : RX);
  const int cnt_x = QX + (xcd < RX ? 1 : 0);
  const int cnt = (cnt_x - loc + 31) >> 5;   // tiles for this block (stride 32)

  const int lane = tid & 63;
  const int wave = tid >> 6;
  const int l15 = lane & 15, quad = lane >> 4;
  const int wr = wave >> 2, wc = wave & 3;
  const int wm = wr * 128, wn = wc * 64;

  // per-thread staging geometry (loop-invariant)
  const int st_r = tid >> 3;
  const int st_c = (tid & 7) ^ (st_r & 7);

  auto STAGE = [&](const uint16_t* src, int rowbase, int kt, int slot) {
#pragma unroll
    for (int jj = 0; jj < 2; ++jj) {
      const int row = rowbase + st_r + jj * 64;
      async16(src + (size_t)row * KDIM + kt * 64 + st_c * 8,
              (uint8_t*)(lds + slot * 8192) + tid * 16 + jj * 8192);
    }
  };

  // loop-invariant fragment-read swizzle offsets (rA&7 == rB&7 == l15&7)
  const int sw0 = (quad ^ (l15 & 7)) * 8;
  const int sw1 = ((4 + quad) ^ (l15 & 7)) * 8;
  const uint16_t* Aslot = lds + (size_t)wr * 8192;
  const uint16_t* Bslot = lds + (size_t)(4 + (wc >> 1)) * 8192;
  const int rBb = (wc & 1) * 64;

  // tile coordinates: cur + next (tile v(tv) = base_x + loc + tv*32)
  const int v0 = base_x + loc;
  int tm = (v0 / NBX) * 256, tn = (v0 % NBX) * 256;
  int tmn = tm, tnn = tn;
  if (cnt > 1) {
    const int v1 = v0 + 32;
    tmn = (v1 / NBX) * 256;
    tnn = (v1 % NBX) * 256;
  }

  // prologue: first tile K-tiles 0 (A slots 0,1; B slots 4,5) and 1 (B slots 6,7)
  STAGE(A, tm, 0, 0);
  STAGE(A, tm + 128, 0, 1);
  STAGE(B, tn, 0, 4);
  STAGE(B, tn + 128, 0, 5);
  STAGE(B, tn, 1, 6);
  STAGE(B, tn + 128, 1, 7);
  asm volatile("s_waitcnt vmcnt(4)" ::: "memory");
  __builtin_amdgcn_s_barrier();

#pragma unroll 1
  for (int tv = 0; tv < cnt; ++tv) {
    f32x4 acc[8][4];
#pragma unroll
    for (int mi = 0; mi < 8; mi++)
#pragma unroll
      for (int ni = 0; ni < 4; ni++) acc[mi][ni] = f4zero();

    const bool lastT = (tv == cnt - 1);
#pragma unroll 1
    for (int j = 0; j < 6; ++j) {
      const int S = 2 * j;
      const bool cross = (j == 5);           // S+2==12, S+3==13 -> next tile
      const bool ok2 = !cross || !lastT;
      const bool ok3 = !cross || !lastT;
      const int k2 = cross ? 0 : S + 2;
      const int k3 = cross ? 1 : S + 3;
      const int am2 = cross ? tmn : tm;
      const int bn2 = cross ? tnn : tn;
      const int bn3 = cross ? tnn : tn;
#pragma unroll
      for (int pb = 0; pb < 2; ++pb) {
        bf16x8 bfr[4][2];
#pragma unroll
        for (int q = 0; q < 4; ++q) {
          // ---- ds reads for this phase
          if (q == 0) {
#pragma unroll
            for (int ni = 0; ni < 4; ++ni) {
              const int rB = rBb + ni * 16 + l15;
              const uint16_t* bp = Bslot + pb * 16384 + rB * 64;
              bfr[ni][0] = *(const bf16x8*)(bp + sw0);
              bfr[ni][1] = *(const bf16x8*)(bp + sw1);
            }
          }
          bf16x8 af[2][2];
#pragma unroll
          for (int m2 = 0; m2 < 2; ++m2) {
            const int rA = (q * 2 + m2) * 16 + l15;
            const uint16_t* ap = Aslot + pb * 16384 + rA * 64;
            af[m2][0] = *(const bf16x8*)(ap + sw0);
            af[m2][1] = *(const bf16x8*)(ap + sw1);
          }
          // ---- stage one half-tile per schedule
          if (pb == 0) {
            if (q == 0) STAGE(A, tm, S + 1, 2);
            else if (q == 1) STAGE(A, tm + 128, S + 1, 3);
            else if (q == 2) { if (ok2) STAGE(B, bn2, k2, 4); }
            else { if (ok2) STAGE(B, bn2 + 128, k2, 5); }
          } else {
            if (q == 0) { if (ok2) STAGE(A, am2, k2, 0); }
            else if (q == 1) { if (ok2) STAGE(A, am2 + 128, k2, 1); }
            else if (q == 2) { if (ok3) STAGE(B, bn3, k3, 6); }
            else { if (ok3) STAGE(B, bn3 + 128, k3, 7); }
          }
          __builtin_amdgcn_s_barrier();
          asm volatile("s_waitcnt lgkmcnt(0)" ::: "memory");
          __builtin_amdgcn_sched_barrier(0);
          __builtin_amdgcn_s_setprio(1);
#pragma unroll
          for (int kk = 0; kk < 2; ++kk)
#pragma unroll
            for (int m2 = 0; m2 < 2; ++m2)
#pragma unroll
              for (int ni = 0; ni < 4; ++ni)
                acc[q * 2 + m2][ni] = mfma16(bfr[ni][kk], af[m2][kk], acc[q * 2 + m2][ni]);
          __builtin_amdgcn_s_setprio(0);
          if (q == 3) {
            const bool keep = (pb == 0) ? ok2 : ok3;
            if (keep) asm volatile("s_waitcnt vmcnt(4)" ::: "memory");
            else asm volatile("s_waitcnt vmcnt(0)" ::: "memory");
          }
          __builtin_amdgcn_s_barrier();
        }
      }
    }

    // ---- epilogue (acc is C^T: row quad*4+rg = n, col l15 = m)
#pragma unroll
    for (int ni = 0; ni < 4; ++ni) {
      const int n0 = tn + wn + ni * 16 + quad * 4;
      const float4 bb = *(const float4*)(bias + n0);
      if (EPI == 0) {
        const int which = n0 / HIDDEN;
        const int rem = n0 - which * HIDDEN;
        const int head = rem >> 6, d0 = rem & 63;
        const float sc = (which == 0) ? 0.125f : 1.f;
        const size_t cA = (size_t)which * BH * HW * 64 + (size_t)head * HW * 64 + d0;
#pragma unroll
        for (int mi = 0; mi < 8; ++mi) {
          const int m = tm + wm + mi * 16 + l15;
          const int b_ = m / HW;
          const int s_ = m - b_ * HW;
          ushort4 o;
          o.x = f2bf((acc[mi][ni][0] + bb.x) * sc);
          o.y = f2bf((acc[mi][ni][1] + bb.y) * sc);
          o.z = f2bf((acc[mi][ni][2] + bb.z) * sc);
          o.w = f2bf((acc[mi][ni][3] + bb.w) * sc);
          *(ushort4*)((uint16_t*)outp + cA + ((size_t)b_ * NH) * HW * 64 + (size_t)s_ * 64) = o;
        }
      } else {
#pragma unroll
        for (int mi = 0; mi < 8; ++mi) {
          const int m = tm + wm + mi * 16 + l15;
          float4 o;
          o.x = acc[mi][ni][0] + bb.x;
          o.y = acc[mi][ni][1] + bb.y;
          o.z = acc[mi][ni][2] + bb.z;
          o.w = acc[mi][ni][3] + bb.w;
          *(float4*)((float*)outp + (size_t)m * HIDDEN + n0) = o;
        }
      }
    }

    // ---- advance tile coords (next-next computed for staging lookahead)
    tm = tmn; tn = tnn;
    if (tv + 2 < cnt) {
      const int v2 = base_x + loc + (tv + 2) * 32;
      tmn = (v2 / NBX) * 256;
      tnn = (v2 % NBX) * 256;
    }
  }
}

// ---------------- fused attention (swapped-operand form) ----------------
__global__ __launch_bounds__(256, 4) void attn_kernel(const uint16_t* __restrict__ qkv,
                                                      const uint16_t* __restrict__ Rt,
                                                      uint16_t* __restrict__ aout) {
  __shared__ __align__(16) uint8_t smem[37376];
  uint16_t* Ks = (uint16_t*)smem;              // [208][64] chunk-swizzled
  uint16_t* Vt = (uint16_t*)smem;              // [64][224] kappa-order, chunk-swizzled
  uint16_t* Ts = (uint16_t*)(smem + 28672);    // [64][68]: T^T[r][q_local]

  const int wgid = blockIdx.x;                 // 0..12287
  const int jsw = (wgid & 7) * 1536 + (wgid >> 3);  // XCD swizzle (12288 % 8 == 0)
  const int qt = jsw & 3;
  const int bh = jsw >> 2;
  const int q0 = qt * 64;
  const int tid = threadIdx.x;
  const int wave = tid >> 6, lane = tid & 63;
  const int l15 = lane & 15, quad = lane >> 4;

  const uint16_t* qg = qkv + (size_t)bh * HW * 64;
  const uint16_t* kg = qkv + ((size_t)BH + bh) * HW * 64;
  const uint16_t* vg = qkv + ((size_t)2 * BH + bh) * HW * 64;

  // ---- stage K -> Ks, chunk-swizzled: (r, chunk c) at r*64 + (c^(r&7))*8
#pragma unroll
  for (int i = 0; i < 7; i++) {
    const int c = tid + i * 256;
    if (c < 1568) {
      const int r = c >> 3, ch = c & 7;
      uint4 v = *(const uint4*)(kg + (size_t)r * 64 + ch * 8);
      *(uint4*)(Ks + r * 64 + ((ch ^ (r & 7)) * 8)) = v;
    }
  }

  // ---- Q fragment straight from global (b-operand: row=l15, chunk=quad)
  const int qrow = q0 + wave * 16 + l15;       // this lane's q row
  const int qr = (qrow < HW) ? qrow : (HW - 1);
  bf16x8 qb0 = *(const bf16x8*)(qg + (size_t)qr * 64 + quad * 8);
  bf16x8 qb1 = *(const bf16x8*)(qg + (size_t)qr * 64 + 32 + quad * 8);

  // ---- T^T = Rt * Q^T : lane holds T^T[r = t*16+quad*4+rg][q=l15]; spill to Ts
  {
    f32x4 racc[4];
#pragma unroll
    for (int t = 0; t < 4; t++) racc[t] = f4zero();
    __builtin_amdgcn_s_setprio(1);
#pragma unroll
    for (int t = 0; t < 4; t++) {
      bf16x8 r0 = *(const bf16x8*)(Rt + (t * 16 + l15) * 64 + quad * 8);
      bf16x8 r1 = *(const bf16x8*)(Rt + (t * 16 + l15) * 64 + 32 + quad * 8);
      racc[t] = mfma16(r0, qb0, racc[t]);
      racc[t] = mfma16(r1, qb1, racc[t]);
    }
    __builtin_amdgcn_s_setprio(0);
#pragma unroll
    for (int t = 0; t < 4; t++)
#pragma unroll
      for (int rg = 0; rg < 4; rg++)
        Ts[(t * 16 + quad * 4 + rg) * 68 + wave * 16 + l15] = f2bf(racc[t][rg]);
  }

  __syncthreads();  // Ks staged (Ts writes also ordered before all later reads)

  // ---- prefetch V into registers (latency hidden under S-phase MFMAs)
  uint4 vreg[7];
#pragma unroll
  for (int i = 0; i < 7; i++) {
    const int c = tid + i * 256;
    vreg[i] = (c < 1568) ? *(const uint4*)(vg + (size_t)c * 8) : make_uint4(0u, 0u, 0u, 0u);
  }

  // ---- S^T = K * Q^T : lane holds S[j = t*16+quad*4+rg][its own q]
  f32x4 sacc[13];
#pragma unroll
  for (int t = 0; t < 13; t++) sacc[t] = f4zero();
  {
    const int sw0 = (quad ^ (l15 & 7)) * 8;
    const int sw1 = ((quad + 4) ^ (l15 & 7)) * 8;
    __builtin_amdgcn_s_setprio(1);
#pragma unroll
    for (int t = 0; t < 13; t++) {
      const uint16_t* kr = Ks + (t * 16 + l15) * 64;
      bf16x8 a0 = *(const bf16x8*)(kr + sw0);
      bf16x8 a1 = *(const bf16x8*)(kr + sw1);
      sacc[t] = mfma16(a0, qb0, sacc[t]);
      sacc[t] = mfma16(a1, qb1, sacc[t]);
    }
    __builtin_amdgcn_s_setprio(0);
  }

  __syncthreads();  // all waves done reading Ks; V loads drained before overlay

  // ---- zero the kappa-tail columns [196,224) of Vt (one store per thread)
  {
    const int d = tid & 63, wv = tid >> 6;
    if (wv == 0) *(uint2*)(Vt + d * 224 + 196) = make_uint2(0u, 0u);
    else *(uint4*)(Vt + d * 224 + 200 + (wv - 1) * 8) = make_uint4(0u, 0u, 0u, 0u);
  }

  // ---- V^T into Vt in kappa-order, swizzled; writes are bank-conflict-free
  // kappa(j): j = t*16 + qj*4 + rg  ->  (t>>1)*32 + qj*8 + (t&1)*4 + rg
#pragma unroll
  for (int i = 0; i < 7; i++) {
    const int c = tid + i * 256;
    if (c < 1568) {
      const int jj = c >> 3;
      const int dp = c & 7;               // d block: rows dp*8 .. dp*8+7
      const int tt = jj >> 4;
      const int kap = (tt >> 1) * 32 + ((jj >> 2) & 3) * 8 + (tt & 1) * 4 + (jj & 3);
      const int cj = kap >> 3;
      const int chs = (cj < 24) ? ((cj & 24) | ((cj & 7) ^ dp)) : cj;
      uint16_t* dst = Vt + dp * 8 * 224 + chs * 8 + (kap & 7);
      const uint16_t* pe = (const uint16_t*)&vreg[i];
#pragma unroll
      for (int e = 0; e < 8; e++) dst[e * 224] = pe[e];
    }
  }

  // ---- softmax fully in registers (row = lane's own q); bias from Ts
  uint32_t P2[13][2];
  {
    const int hq = (qr * 586) >> 13;      // qr / 14
    const int wq = qr - hq * 14;
    const uint16_t* Tb = Ts + wave * 16 + l15;   // column base, rows stride 68
    const int c0 = (hq + 13) * 68;
    const int c1 = (wq + 45) * 68;
    float mx0 = -1e30f, mx1 = -1e30f, mx2 = -1e30f, mx3 = -1e30f;
#pragma unroll
    for (int t = 0; t < 13; t++) {
#pragma unroll
      for (int rg = 0; rg < 4; rg++) {
        const int j = t * 16 + quad * 4 + rg;
        const int kh = (j * 586) >> 13;   // j / 14 (valid for j <= 195)
        const int kw = j - kh * 14;
        const float b = bf2f(Tb[c0 - kh * 68]) + bf2f(Tb[c1 - kw * 68]);
        float s = sacc[t][rg] + b;
        s = (j < HW) ? s : -1e30f;
        sacc[t][rg] = s;
        if (rg == 0) mx0 = fmaxf(mx0, s);
        else if (rg == 1) mx1 = fmaxf(mx1, s);
        else if (rg == 2) mx2 = fmaxf(mx2, s);
        else mx3 = fmaxf(mx3, s);
      }
    }
    float mx = fmaxf(fmaxf(mx0, mx1), fmaxf(mx2, mx3));
    mx = fmaxf(mx, __shfl_xor(mx, 16, 64));
    mx = fmaxf(mx, __shfl_xor(mx, 32, 64));
    float s0 = 0.f, s1 = 0.f, s2 = 0.f, s3 = 0.f;
#pragma unroll
    for (int t = 0; t < 13; t++) {
#pragma unroll
      for (int rg = 0; rg < 4; rg++) {
        const float p = __expf(sacc[t][rg] - mx);
        sacc[t][rg] = p;
        if (rg == 0) s0 += p;
        else if (rg == 1) s1 += p;
        else if (rg == 2) s2 += p;
        else s3 += p;
      }
    }
    float sum = (s0 + s1) + (s2 + s3);
    sum += __shfl_xor(sum, 16, 64);
    sum += __shfl_xor(sum, 32, 64);
    const float inv = 1.f / sum;
#pragma unroll
    for (int t = 0; t < 13; t++) {
      P2[t][0] = pack2bf(sacc[t][0] * inv, sacc[t][1] * inv);
      P2[t][1] = pack2bf(sacc[t][2] * inv, sacc[t][3] * inv);
    }
  }

  __syncthreads();  // all Vt writes visible before PV reads

  // ---- O = P*V : A-fragment is the lane's own P2 registers (kappa order)
  f32x4 oacc[4];
#pragma unroll
  for (int nt = 0; nt < 4; nt++) oacc[nt] = f4zero();
  {
    __builtin_amdgcn_s_setprio(1);
#pragma unroll
    for (int ks = 0; ks < 7; ks++) {
      uint4 aw;
      aw.x = P2[2 * ks][0];
      aw.y = P2[2 * ks][1];
      aw.z = (ks < 6) ? P2[2 * ks + 1][0] : 0u;
      aw.w = (ks < 6) ? P2[2 * ks + 1][1] : 0u;
      const bf16x8 af = __builtin_bit_cast(bf16x8, aw);
      const int cb = ks * 4 + quad;       // kappa chunk
#pragma unroll
      for (int nt = 0; nt < 4; nt++) {
        const int d = nt * 16 + l15;
        const int p = (d >> 3) & 7;
        const int chs = (cb < 24) ? ((cb & 24) | ((cb & 7) ^ p)) : cb;
        bf16x8 bv = *(const bf16x8*)(Vt + d * 224 + chs * 8);
        oacc[nt] = mfma16(af, bv, oacc[nt]);
      }
    }
    __builtin_amdgcn_s_setprio(0);
  }

  const int b = bh / NH, head = bh - b * NH;
#pragma unroll
  for (int nt = 0; nt < 4; nt++) {
#pragma unroll
    for (int rg = 0; rg < 4; rg++) {
      const int qro = q0 + wave * 16 + quad * 4 + rg;
      if (qro < HW) {
        const int d = nt * 16 + l15;
        aout[((size_t)b * HW + qro) * HIDDEN + head * 64 + d] = f2bf(oacc[nt][rg]);
      }
    }
  }
}

extern "C" void kernel_launch(void* const* d_in, const int* in_sizes, int n_in,
                              void* d_out, int out_size, void* d_ws, size_t ws_size,
                              hipStream_t stream) {
  const float* hidden = (const float*)d_in[0];
  const float* qkv_w = (const float*)d_in[1];
  const float* qkv_b = (const float*)d_in[2];
  const float* proj_w = (const float*)d_in[3];
  const float* proj_b = (const float*)d_in[4];
  const float* rel_h = (const float*)d_in[5];
  const float* rel_w = (const float*)d_in[6];

  uint8_t* ws = (uint8_t*)d_ws;
  uint16_t* Xb = (uint16_t*)(ws);                  // 77,070,336 B; reused as attn_out
  uint16_t* qkvb = (uint16_t*)(ws + 77070336);     // 231,211,008 B: [3][3072][196][64] bf16
  uint16_t* Rt = (uint16_t*)(ws + 308281344);      // 8,192 B: [64][64] bf16 rel table
  uint16_t* wqkvb = (uint16_t*)(ws + 308289536);   // 3,538,944 B
  uint16_t* wprjb = (uint16_t*)(ws + 311828480);   // 1,179,648 B

  prep<<<5712, 256, 0, stream>>>(hidden, qkv_w, proj_w, rel_h, rel_w,
                                 Xb, wqkvb, wprjb, Rt);

  gemm_bt<0><<<256, 512, 0, stream>>>(Xb, wqkvb, qkv_b, (void*)qkvb);
  attn_kernel<<<dim3(12288), 256, 0, stream>>>(qkvb, Rt, Xb);
  gemm_bt<1><<<256, 512, 0, stream>>>(Xb, wprjb, proj_b, d_out);
}

// Round 6
// 729.779 us; speedup vs baseline: 1.0195x; 1.0013x over previous
//
#include <hip/hip_runtime.h>
#include <stdint.h>

#define WIN 14
#define HW 196
#define NH 12
#define HIDDEN 768
#define BH 3072
#define MTOT 50176
#define KDIM 768

typedef __bf16 bf16x8 __attribute__((ext_vector_type(8)));
typedef float f32x4 __attribute__((ext_vector_type(4)));

__device__ __forceinline__ float bf2f(uint16_t u) {
  union { uint32_t i; float f; } v; v.i = ((uint32_t)u) << 16; return v.f;
}
__device__ __forceinline__ uint16_t f2bf(float f) {
  uint32_t u = __float_as_uint(f);
  uint32_t r = u + 0x7FFFu + ((u >> 16) & 1u);
  return (uint16_t)(r >> 16);
}
__device__ __forceinline__ uint32_t pack2bf(float a, float b) {
  return (uint32_t)f2bf(a) | ((uint32_t)f2bf(b) << 16);
}
__device__ __forceinline__ f32x4 mfma16(bf16x8 a, bf16x8 b, f32x4 c) {
  return __builtin_amdgcn_mfma_f32_16x16x32_bf16(a, b, c, 0, 0, 0);
}
__device__ __forceinline__ f32x4 f4zero() { f32x4 z = {0.f, 0.f, 0.f, 0.f}; return z; }

__device__ __forceinline__ void async16(const void* g, void* l) {
#if __has_builtin(__builtin_amdgcn_global_load_lds)
  __builtin_amdgcn_global_load_lds((__attribute__((address_space(1))) void*)g,
                                   (__attribute__((address_space(3))) void*)l, 16, 0, 0);
#else
  *(uint4*)l = *(const uint4*)g;
#endif
}

// ---------------- fused prep: 3x fp32->bf16 convert + rel-pos table ----------------
// blocks [0,4096): hidden; [4096,5120): qkv_w; [5120,5696): proj_w; [5696,5712): Rt.
__global__ __launch_bounds__(256) void prep(const float* __restrict__ hidden,
                                            const float* __restrict__ qkv_w,
                                            const float* __restrict__ proj_w,
                                            const float* __restrict__ rh,
                                            const float* __restrict__ rw,
                                            uint16_t* __restrict__ Xb,
                                            uint16_t* __restrict__ wqkvb,
                                            uint16_t* __restrict__ wprjb,
                                            uint16_t* __restrict__ Rt) {
  const int blk = blockIdx.x;
  if (blk < 4096) {
    const int n4 = (MTOT * HIDDEN) / 4;
    int i = blk * 256 + threadIdx.x;
    for (; i < n4; i += 4096 * 256) {
      float4 v = ((const float4*)hidden)[i];
      ushort4 o;
      o.x = f2bf(v.x); o.y = f2bf(v.y); o.z = f2bf(v.z); o.w = f2bf(v.w);
      ((ushort4*)Xb)[i] = o;
    }
  } else if (blk < 5120) {
    const int n4 = (3 * HIDDEN * HIDDEN) / 4;
    int i = (blk - 4096) * 256 + threadIdx.x;
    for (; i < n4; i += 1024 * 256) {
      float4 v = ((const float4*)qkv_w)[i];
      ushort4 o;
      o.x = f2bf(v.x); o.y = f2bf(v.y); o.z = f2bf(v.z); o.w = f2bf(v.w);
      ((ushort4*)wqkvb)[i] = o;
    }
  } else if (blk < 5696) {
    const int n4 = (HIDDEN * HIDDEN) / 4;
    int i = (blk - 5120) * 256 + threadIdx.x;
    if (i < n4) {
      float4 v = ((const float4*)proj_w)[i];
      ushort4 o;
      o.x = f2bf(v.x); o.y = f2bf(v.y); o.z = f2bf(v.z); o.w = f2bf(v.w);
      ((ushort4*)wprjb)[i] = o;
    }
  } else {
    const int i = (blk - 5696) * 256 + threadIdx.x;
    if (i < 4096) {
      const int r = i >> 6, c = i & 63;
      float v = 0.f;
      if (r < 27) v = rh[r * 64 + c] * 8.f;
      else if (r >= 32 && r < 59) v = rw[(r - 32) * 64 + c] * 8.f;
      Rt[i] = f2bf(v);
    }
  }
}

// ---------------- GEMM: C[m][n] = sum_k A[m][k]*B[n][k] (+bias), bf16 in, K=768 ----
// PERSISTENT, XCD-LOCAL (see R5 comment). 8-phase double-barrier schedule
// (T3+T4+T5); virtual continuous K-stream across tile boundaries. MFMA operands
// swapped (acc = C^T). EPILOGUE: mi-outer / ni-inner so the 4 stores completing
// each 128B output line are back-to-back (L2 write-combine before eviction) —
// fixes the 1.55x WRITE amplification measured in R4/R5.
template <int EPI>
__global__ __launch_bounds__(512, 2) void gemm_bt(const uint16_t* __restrict__ A,
                                                  const uint16_t* __restrict__ B,
                                                  const float* __restrict__ bias,
                                                  void* __restrict__ outp) {
  constexpr int NBX = (EPI == 0) ? 9 : 3;
  constexpr int NTILES = (EPI == 0) ? 1764 : 588;
  constexpr int QX = NTILES / 8, RX = NTILES % 8;
  __shared__ __align__(16) uint16_t lds[8 * 8192];  // 128 KB

  const int tid = threadIdx.x;
  const int p = blockIdx.x;                  // 0..255
  const int xcd = p & 7, loc = p >> 3;       // hw round-robin: block p -> XCD p%8
  const int base_x = xcd * QX + (xcd < RX ? xcd : RX);
  const int cnt_x = QX + (xcd < RX ? 1 : 0);
  const int cnt = (cnt_x - loc + 31) >> 5;   // tiles for this block (stride 32)

  const int lane = tid & 63;
  const int wave = tid >> 6;
  const int l15 = lane & 15, quad = lane >> 4;
  const int wr = wave >> 2, wc = wave & 3;
  const int wm = wr * 128, wn = wc * 64;

  // per-thread staging geometry (loop-invariant)
  const int st_r = tid >> 3;
  const int st_c = (tid & 7) ^ (st_r & 7);

  auto STAGE = [&](const uint16_t* src, int rowbase, int kt, int slot) {
#pragma unroll
    for (int jj = 0; jj < 2; ++jj) {
      const int row = rowbase + st_r + jj * 64;
      async16(src + (size_t)row * KDIM + kt * 64 + st_c * 8,
              (uint8_t*)(lds + slot * 8192) + tid * 16 + jj * 8192);
    }
  };

  // loop-invariant fragment-read swizzle offsets (rA&7 == rB&7 == l15&7)
  const int sw0 = (quad ^ (l15 & 7)) * 8;
  const int sw1 = ((4 + quad) ^ (l15 & 7)) * 8;
  const uint16_t* Aslot = lds + (size_t)wr * 8192;
  const uint16_t* Bslot = lds + (size_t)(4 + (wc >> 1)) * 8192;
  const int rBb = (wc & 1) * 64;

  // tile coordinates: cur + next (tile v(tv) = base_x + loc + tv*32)
  const int v0 = base_x + loc;
  int tm = (v0 / NBX) * 256, tn = (v0 % NBX) * 256;
  int tmn = tm, tnn = tn;
  if (cnt > 1) {
    const int v1 = v0 + 32;
    tmn = (v1 / NBX) * 256;
    tnn = (v1 % NBX) * 256;
  }

  // prologue: first tile K-tiles 0 (A slots 0,1; B slots 4,5) and 1 (B slots 6,7)
  STAGE(A, tm, 0, 0);
  STAGE(A, tm + 128, 0, 1);
  STAGE(B, tn, 0, 4);
  STAGE(B, tn + 128, 0, 5);
  STAGE(B, tn, 1, 6);
  STAGE(B, tn + 128, 1, 7);
  asm volatile("s_waitcnt vmcnt(4)" ::: "memory");
  __builtin_amdgcn_s_barrier();

#pragma unroll 1
  for (int tv = 0; tv < cnt; ++tv) {
    f32x4 acc[8][4];
#pragma unroll
    for (int mi = 0; mi < 8; mi++)
#pragma unroll
      for (int ni = 0; ni < 4; ni++) acc[mi][ni] = f4zero();

    const bool lastT = (tv == cnt - 1);
#pragma unroll 1
    for (int j = 0; j < 6; ++j) {
      const int S = 2 * j;
      const bool cross = (j == 5);           // S+2==12, S+3==13 -> next tile
      const bool ok2 = !cross || !lastT;
      const bool ok3 = !cross || !lastT;
      const int k2 = cross ? 0 : S + 2;
      const int k3 = cross ? 1 : S + 3;
      const int am2 = cross ? tmn : tm;
      const int bn2 = cross ? tnn : tn;
      const int bn3 = cross ? tnn : tn;
#pragma unroll
      for (int pb = 0; pb < 2; ++pb) {
        bf16x8 bfr[4][2];
#pragma unroll
        for (int q = 0; q < 4; ++q) {
          // ---- ds reads for this phase
          if (q == 0) {
#pragma unroll
            for (int ni = 0; ni < 4; ++ni) {
              const int rB = rBb + ni * 16 + l15;
              const uint16_t* bp = Bslot + pb * 16384 + rB * 64;
              bfr[ni][0] = *(const bf16x8*)(bp + sw0);
              bfr[ni][1] = *(const bf16x8*)(bp + sw1);
            }
          }
          bf16x8 af[2][2];
#pragma unroll
          for (int m2 = 0; m2 < 2; ++m2) {
            const int rA = (q * 2 + m2) * 16 + l15;
            const uint16_t* ap = Aslot + pb * 16384 + rA * 64;
            af[m2][0] = *(const bf16x8*)(ap + sw0);
            af[m2][1] = *(const bf16x8*)(ap + sw1);
          }
          // ---- stage one half-tile per schedule
          if (pb == 0) {
            if (q == 0) STAGE(A, tm, S + 1, 2);
            else if (q == 1) STAGE(A, tm + 128, S + 1, 3);
            else if (q == 2) { if (ok2) STAGE(B, bn2, k2, 4); }
            else { if (ok2) STAGE(B, bn2 + 128, k2, 5); }
          } else {
            if (q == 0) { if (ok2) STAGE(A, am2, k2, 0); }
            else if (q == 1) { if (ok2) STAGE(A, am2 + 128, k2, 1); }
            else if (q == 2) { if (ok3) STAGE(B, bn3, k3, 6); }
            else { if (ok3) STAGE(B, bn3 + 128, k3, 7); }
          }
          __builtin_amdgcn_s_barrier();
          asm volatile("s_waitcnt lgkmcnt(0)" ::: "memory");
          __builtin_amdgcn_sched_barrier(0);
          __builtin_amdgcn_s_setprio(1);
#pragma unroll
          for (int kk = 0; kk < 2; ++kk)
#pragma unroll
            for (int m2 = 0; m2 < 2; ++m2)
#pragma unroll
              for (int ni = 0; ni < 4; ++ni)
                acc[q * 2 + m2][ni] = mfma16(bfr[ni][kk], af[m2][kk], acc[q * 2 + m2][ni]);
          __builtin_amdgcn_s_setprio(0);
          if (q == 3) {
            const bool keep = (pb == 0) ? ok2 : ok3;
            if (keep) asm volatile("s_waitcnt vmcnt(4)" ::: "memory");
            else asm volatile("s_waitcnt vmcnt(0)" ::: "memory");
          }
          __builtin_amdgcn_s_barrier();
        }
      }
    }

    // ---- epilogue (acc is C^T: row quad*4+rg = n, col l15 = m)
    // mi outer / ni inner: the 4 stores covering each 128B line are adjacent.
    if (EPI == 0) {
      const int n0w = tn + wn;                 // 64-aligned: one (which,head) slice
      const int which = n0w / HIDDEN;
      const int head = (n0w - which * HIDDEN) >> 6;
      const float sc = (which == 0) ? 0.125f : 1.f;
      float4 bb[4];
#pragma unroll
      for (int ni = 0; ni < 4; ++ni)
        bb[ni] = *(const float4*)(bias + n0w + ni * 16 + quad * 4);
      uint16_t* obase = (uint16_t*)outp + ((size_t)which * BH + head) * HW * 64;
#pragma unroll
      for (int mi = 0; mi < 8; ++mi) {
        const int m = tm + wm + mi * 16 + l15;
        const int b_ = m / HW;
        const int s_ = m - b_ * HW;
        uint16_t* rowp = obase + ((size_t)b_ * NH * HW + s_) * 64 + quad * 4;
#pragma unroll
        for (int ni = 0; ni < 4; ++ni) {
          ushort4 o;
          o.x = f2bf((acc[mi][ni][0] + bb[ni].x) * sc);
          o.y = f2bf((acc[mi][ni][1] + bb[ni].y) * sc);
          o.z = f2bf((acc[mi][ni][2] + bb[ni].z) * sc);
          o.w = f2bf((acc[mi][ni][3] + bb[ni].w) * sc);
          *(ushort4*)(rowp + ni * 16) = o;
        }
      }
    } else {
      float4 bb[4];
#pragma unroll
      for (int ni = 0; ni < 4; ++ni)
        bb[ni] = *(const float4*)(bias + tn + wn + ni * 16 + quad * 4);
#pragma unroll
      for (int mi = 0; mi < 8; ++mi) {
        const int m = tm + wm + mi * 16 + l15;
        float* rowp = (float*)outp + (size_t)m * HIDDEN + tn + wn + quad * 4;
#pragma unroll
        for (int ni = 0; ni < 4; ++ni) {
          float4 o;
          o.x = acc[mi][ni][0] + bb[ni].x;
          o.y = acc[mi][ni][1] + bb[ni].y;
          o.z = acc[mi][ni][2] + bb[ni].z;
          o.w = acc[mi][ni][3] + bb[ni].w;
          *(float4*)(rowp + ni * 16) = o;
        }
      }
    }

    // ---- advance tile coords (next-next computed for staging lookahead)
    tm = tmn; tn = tnn;
    if (tv + 2 < cnt) {
      const int v2 = base_x + loc + (tv + 2) * 32;
      tmn = (v2 / NBX) * 256;
      tnn = (v2 % NBX) * 256;
    }
  }
}

// ---------------- fused attention (swapped-operand form) ----------------
__global__ __launch_bounds__(256, 4) void attn_kernel(const uint16_t* __restrict__ qkv,
                                                      const uint16_t* __restrict__ Rt,
                                                      uint16_t* __restrict__ aout) {
  __shared__ __align__(16) uint8_t smem[37376];
  uint16_t* Ks = (uint16_t*)smem;              // [208][64] chunk-swizzled
  uint16_t* Vt = (uint16_t*)smem;              // [64][224] kappa-order, chunk-swizzled
  uint16_t* Ts = (uint16_t*)(smem + 28672);    // [64][68]: T^T[r][q_local]

  const int wgid = blockIdx.x;                 // 0..12287
  const int jsw = (wgid & 7) * 1536 + (wgid >> 3);  // XCD swizzle (12288 % 8 == 0)
  const int qt = jsw & 3;
  const int bh = jsw >> 2;
  const int q0 = qt * 64;
  const int tid = threadIdx.x;
  const int wave = tid >> 6, lane = tid & 63;
  const int l15 = lane & 15, quad = lane >> 4;

  const uint16_t* qg = qkv + (size_t)bh * HW * 64;
  const uint16_t* kg = qkv + ((size_t)BH + bh) * HW * 64;
  const uint16_t* vg = qkv + ((size_t)2 * BH + bh) * HW * 64;

  // ---- stage K -> Ks, chunk-swizzled: (r, chunk c) at r*64 + (c^(r&7))*8
#pragma unroll
  for (int i = 0; i < 7; i++) {
    const int c = tid + i * 256;
    if (c < 1568) {
      const int r = c >> 3, ch = c & 7;
      uint4 v = *(const uint4*)(kg + (size_t)r * 64 + ch * 8);
      *(uint4*)(Ks + r * 64 + ((ch ^ (r & 7)) * 8)) = v;
    }
  }

  // ---- Q fragment straight from global (b-operand: row=l15, chunk=quad)
  const int qrow = q0 + wave * 16 + l15;       // this lane's q row
  const int qr = (qrow < HW) ? qrow : (HW - 1);
  bf16x8 qb0 = *(const bf16x8*)(qg + (size_t)qr * 64 + quad * 8);
  bf16x8 qb1 = *(const bf16x8*)(qg + (size_t)qr * 64 + 32 + quad * 8);

  // ---- T^T = Rt * Q^T : lane holds T^T[r = t*16+quad*4+rg][q=l15]; spill to Ts
  {
    f32x4 racc[4];
#pragma unroll
    for (int t = 0; t < 4; t++) racc[t] = f4zero();
    __builtin_amdgcn_s_setprio(1);
#pragma unroll
    for (int t = 0; t < 4; t++) {
      bf16x8 r0 = *(const bf16x8*)(Rt + (t * 16 + l15) * 64 + quad * 8);
      bf16x8 r1 = *(const bf16x8*)(Rt + (t * 16 + l15) * 64 + 32 + quad * 8);
      racc[t] = mfma16(r0, qb0, racc[t]);
      racc[t] = mfma16(r1, qb1, racc[t]);
    }
    __builtin_amdgcn_s_setprio(0);
#pragma unroll
    for (int t = 0; t < 4; t++)
#pragma unroll
      for (int rg = 0; rg < 4; rg++)
        Ts[(t * 16 + quad * 4 + rg) * 68 + wave * 16 + l15] = f2bf(racc[t][rg]);
  }

  __syncthreads();  // Ks staged (Ts writes also ordered before all later reads)

  // ---- prefetch V into registers (latency hidden under S-phase MFMAs)
  uint4 vreg[7];
#pragma unroll
  for (int i = 0; i < 7; i++) {
    const int c = tid + i * 256;
    vreg[i] = (c < 1568) ? *(const uint4*)(vg + (size_t)c * 8) : make_uint4(0u, 0u, 0u, 0u);
  }

  // ---- S^T = K * Q^T : lane holds S[j = t*16+quad*4+rg][its own q]
  f32x4 sacc[13];
#pragma unroll
  for (int t = 0; t < 13; t++) sacc[t] = f4zero();
  {
    const int sw0 = (quad ^ (l15 & 7)) * 8;
    const int sw1 = ((quad + 4) ^ (l15 & 7)) * 8;
    __builtin_amdgcn_s_setprio(1);
#pragma unroll
    for (int t = 0; t < 13; t++) {
      const uint16_t* kr = Ks + (t * 16 + l15) * 64;
      bf16x8 a0 = *(const bf16x8*)(kr + sw0);
      bf16x8 a1 = *(const bf16x8*)(kr + sw1);
      sacc[t] = mfma16(a0, qb0, sacc[t]);
      sacc[t] = mfma16(a1, qb1, sacc[t]);
    }
    __builtin_amdgcn_s_setprio(0);
  }

  __syncthreads();  // all waves done reading Ks; V loads drained before overlay

  // ---- zero the kappa-tail columns [196,224) of Vt (one store per thread)
  {
    const int d = tid & 63, wv = tid >> 6;
    if (wv == 0) *(uint2*)(Vt + d * 224 + 196) = make_uint2(0u, 0u);
    else *(uint4*)(Vt + d * 224 + 200 + (wv - 1) * 8) = make_uint4(0u, 0u, 0u, 0u);
  }

  // ---- V^T into Vt in kappa-order, swizzled; writes are bank-conflict-free
  // kappa(j): j = t*16 + qj*4 + rg  ->  (t>>1)*32 + qj*8 + (t&1)*4 + rg
#pragma unroll
  for (int i = 0; i < 7; i++) {
    const int c = tid + i * 256;
    if (c < 1568) {
      const int jj = c >> 3;
      const int dp = c & 7;               // d block: rows dp*8 .. dp*8+7
      const int tt = jj >> 4;
      const int kap = (tt >> 1) * 32 + ((jj >> 2) & 3) * 8 + (tt & 1) * 4 + (jj & 3);
      const int cj = kap >> 3;
      const int chs = (cj < 24) ? ((cj & 24) | ((cj & 7) ^ dp)) : cj;
      uint16_t* dst = Vt + dp * 8 * 224 + chs * 8 + (kap & 7);
      const uint16_t* pe = (const uint16_t*)&vreg[i];
#pragma unroll
      for (int e = 0; e < 8; e++) dst[e * 224] = pe[e];
    }
  }

  // ---- softmax fully in registers (row = lane's own q); bias from Ts
  uint32_t P2[13][2];
  {
    const int hq = (qr * 586) >> 13;      // qr / 14
    const int wq = qr - hq * 14;
    const uint16_t* Tb = Ts + wave * 16 + l15;   // column base, rows stride 68
    const int c0 = (hq + 13) * 68;
    const int c1 = (wq + 45) * 68;
    float mx0 = -1e30f, mx1 = -1e30f, mx2 = -1e30f, mx3 = -1e30f;
#pragma unroll
    for (int t = 0; t < 13; t++) {
#pragma unroll
      for (int rg = 0; rg < 4; rg++) {
        const int j = t * 16 + quad * 4 + rg;
        const int kh = (j * 586) >> 13;   // j / 14 (valid for j <= 195)
        const int kw = j - kh * 14;
        const float b = bf2f(Tb[c0 - kh * 68]) + bf2f(Tb[c1 - kw * 68]);
        float s = sacc[t][rg] + b;
        s = (j < HW) ? s : -1e30f;
        sacc[t][rg] = s;
        if (rg == 0) mx0 = fmaxf(mx0, s);
        else if (rg == 1) mx1 = fmaxf(mx1, s);
        else if (rg == 2) mx2 = fmaxf(mx2, s);
        else mx3 = fmaxf(mx3, s);
      }
    }
    float mx = fmaxf(fmaxf(mx0, mx1), fmaxf(mx2, mx3));
    mx = fmaxf(mx, __shfl_xor(mx, 16, 64));
    mx = fmaxf(mx, __shfl_xor(mx, 32, 64));
    float s0 = 0.f, s1 = 0.f, s2 = 0.f, s3 = 0.f;
#pragma unroll
    for (int t = 0; t < 13; t++) {
#pragma unroll
      for (int rg = 0; rg < 4; rg++) {
        const float p = __expf(sacc[t][rg] - mx);
        sacc[t][rg] = p;
        if (rg == 0) s0 += p;
        else if (rg == 1) s1 += p;
        else if (rg == 2) s2 += p;
        else s3 += p;
      }
    }
    float sum = (s0 + s1) + (s2 + s3);
    sum += __shfl_xor(sum, 16, 64);
    sum += __shfl_xor(sum, 32, 64);
    const float inv = 1.f / sum;
#pragma unroll
    for (int t = 0; t < 13; t++) {
      P2[t][0] = pack2bf(sacc[t][0] * inv, sacc[t][1] * inv);
      P2[t][1] = pack2bf(sacc[t][2] * inv, sacc[t][3] * inv);
    }
  }

  __syncthreads();  // all Vt writes visible before PV reads

  // ---- O = P*V : A-fragment is the lane's own P2 registers (kappa order)
  f32x4 oacc[4];
#pragma unroll
  for (int nt = 0; nt < 4; nt++) oacc[nt] = f4zero();
  {
    __builtin_amdgcn_s_setprio(1);
#pragma unroll
    for (int ks = 0; ks < 7; ks++) {
      uint4 aw;
      aw.x = P2[2 * ks][0];
      aw.y = P2[2 * ks][1];
      aw.z = (ks < 6) ? P2[2 * ks + 1][0] : 0u;
      aw.w = (ks < 6) ? P2[2 * ks + 1][1] : 0u;
      const bf16x8 af = __builtin_bit_cast(bf16x8, aw);
      const int cb = ks * 4 + quad;       // kappa chunk
#pragma unroll
      for (int nt = 0; nt < 4; nt++) {
        const int d = nt * 16 + l15;
        const int p = (d >> 3) & 7;
        const int chs = (cb < 24) ? ((cb & 24) | ((cb & 7) ^ p)) : cb;
        bf16x8 bv = *(const bf16x8*)(Vt + d * 224 + chs * 8);
        oacc[nt] = mfma16(af, bv, oacc[nt]);
      }
    }
    __builtin_amdgcn_s_setprio(0);
  }

  const int b = bh / NH, head = bh - b * NH;
#pragma unroll
  for (int nt = 0; nt < 4; nt++) {
#pragma unroll
    for (int rg = 0; rg < 4; rg++) {
      const int qro = q0 + wave * 16 + quad * 4 + rg;
      if (qro < HW) {
        const int d = nt * 16 + l15;
        aout[((size_t)b * HW + qro) * HIDDEN + head * 64 + d] = f2bf(oacc[nt][rg]);
      }
    }
  }
}

extern "C" void kernel_launch(void* const* d_in, const int* in_sizes, int n_in,
                              void* d_out, int out_size, void* d_ws, size_t ws_size,
                              hipStream_t stream) {
  const float* hidden = (const float*)d_in[0];
  const float* qkv_w = (const float*)d_in[1];
  const float* qkv_b = (const float*)d_in[2];
  const float* proj_w = (const float*)d_in[3];
  const float* proj_b = (const float*)d_in[4];
  const float* rel_h = (const float*)d_in[5];
  const float* rel_w = (const float*)d_in[6];

  uint8_t* ws = (uint8_t*)d_ws;
  uint16_t* Xb = (uint16_t*)(ws);                  // 77,070,336 B; reused as attn_out
  uint16_t* qkvb = (uint16_t*)(ws + 77070336);     // 231,211,008 B: [3][3072][196][64] bf16
  uint16_t* Rt = (uint16_t*)(ws + 308281344);      // 8,192 B: [64][64] bf16 rel table
  uint16_t* wqkvb = (uint16_t*)(ws + 308289536);   // 3,538,944 B
  uint16_t* wprjb = (uint16_t*)(ws + 311828480);   // 1,179,648 B

  prep<<<5712, 256, 0, stream>>>(hidden, qkv_w, proj_w, rel_h, rel_w,
                                 Xb, wqkvb, wprjb, Rt);

  gemm_bt<0><<<256, 512, 0, stream>>>(Xb, wqkvb, qkv_b, (void*)qkvb);
  attn_kernel<<<dim3(12288), 256, 0, stream>>>(qkvb, Rt, Xb);
  gemm_bt<1><<<256, 512, 0, stream>>>(Xb, wprjb, proj_b, d_out);
}

// Round 7
// 708.412 us; speedup vs baseline: 1.0503x; 1.0302x over previous
//
#include <hip/hip_runtime.h>
#include <stdint.h>

#define WIN 14
#define HW 196
#define NH 12
#define HIDDEN 768
#define BH 3072
#define MTOT 50176
#define KDIM 768

typedef __bf16 bf16x8 __attribute__((ext_vector_type(8)));
typedef float f32x4 __attribute__((ext_vector_type(4)));

__device__ __forceinline__ float bf2f(uint16_t u) {
  union { uint32_t i; float f; } v; v.i = ((uint32_t)u) << 16; return v.f;
}
__device__ __forceinline__ uint16_t f2bf(float f) {
  uint32_t u = __float_as_uint(f);
  uint32_t r = u + 0x7FFFu + ((u >> 16) & 1u);
  return (uint16_t)(r >> 16);
}
__device__ __forceinline__ uint32_t pack2bf(float a, float b) {
  return (uint32_t)f2bf(a) | ((uint32_t)f2bf(b) << 16);
}
__device__ __forceinline__ f32x4 mfma16(bf16x8 a, bf16x8 b, f32x4 c) {
  return __builtin_amdgcn_mfma_f32_16x16x32_bf16(a, b, c, 0, 0, 0);
}
__device__ __forceinline__ f32x4 f4zero() { f32x4 z = {0.f, 0.f, 0.f, 0.f}; return z; }

__device__ __forceinline__ void async16(const void* g, void* l) {
#if __has_builtin(__builtin_amdgcn_global_load_lds)
  __builtin_amdgcn_global_load_lds((__attribute__((address_space(1))) void*)g,
                                   (__attribute__((address_space(3))) void*)l, 16, 0, 0);
#else
  *(uint4*)l = *(const uint4*)g;
#endif
}

// ---------------- fused prep: 3x fp32->bf16 convert + rel-pos table ----------------
// blocks [0,4096): hidden; [4096,5120): qkv_w; [5120,5696): proj_w; [5696,5712): Rt.
__global__ __launch_bounds__(256) void prep(const float* __restrict__ hidden,
                                            const float* __restrict__ qkv_w,
                                            const float* __restrict__ proj_w,
                                            const float* __restrict__ rh,
                                            const float* __restrict__ rw,
                                            uint16_t* __restrict__ Xb,
                                            uint16_t* __restrict__ wqkvb,
                                            uint16_t* __restrict__ wprjb,
                                            uint16_t* __restrict__ Rt) {
  const int blk = blockIdx.x;
  if (blk < 4096) {
    const int n4 = (MTOT * HIDDEN) / 4;
    int i = blk * 256 + threadIdx.x;
    for (; i < n4; i += 4096 * 256) {
      float4 v = ((const float4*)hidden)[i];
      ushort4 o;
      o.x = f2bf(v.x); o.y = f2bf(v.y); o.z = f2bf(v.z); o.w = f2bf(v.w);
      ((ushort4*)Xb)[i] = o;
    }
  } else if (blk < 5120) {
    const int n4 = (3 * HIDDEN * HIDDEN) / 4;
    int i = (blk - 4096) * 256 + threadIdx.x;
    for (; i < n4; i += 1024 * 256) {
      float4 v = ((const float4*)qkv_w)[i];
      ushort4 o;
      o.x = f2bf(v.x); o.y = f2bf(v.y); o.z = f2bf(v.z); o.w = f2bf(v.w);
      ((ushort4*)wqkvb)[i] = o;
    }
  } else if (blk < 5696) {
    const int n4 = (HIDDEN * HIDDEN) / 4;
    int i = (blk - 5120) * 256 + threadIdx.x;
    if (i < n4) {
      float4 v = ((const float4*)proj_w)[i];
      ushort4 o;
      o.x = f2bf(v.x); o.y = f2bf(v.y); o.z = f2bf(v.z); o.w = f2bf(v.w);
      ((ushort4*)wprjb)[i] = o;
    }
  } else {
    const int i = (blk - 5696) * 256 + threadIdx.x;
    if (i < 4096) {
      const int r = i >> 6, c = i & 63;
      float v = 0.f;
      if (r < 27) v = rh[r * 64 + c] * 8.f;
      else if (r >= 32 && r < 59) v = rw[(r - 32) * 64 + c] * 8.f;
      Rt[i] = f2bf(v);
    }
  }
}

// ---------------- GEMM: C[m][n] = sum_k A[m][k]*B[n][k] (+bias), bf16 in, K=768 ----
// R3-exact version (best measured: 206 us, WRITE clean). 256x256 tile, BK=64,
// 8 waves (2M x 4N), 8-phase double-barrier schedule (T3+T4+T5).
// LDS = 8 half-tile slots of 16KB (A halves: slots 0..3, B halves: 4..7) = 128 KB.
// Stage placement: P0:A2<-S+1h0, P1:A3<-S+1h1, P2:B0<-S+2h0, P3:B1<-S+2h1,
// P4:A0<-S+2h0, P5:A1<-S+2h1, P6:B2<-S+3h0, P7:B3<-S+3h1.
// Counted waits: vmcnt(4) at end of P3 and P7 only (2 newest halves may fly).
// Swizzle: chunk c at row r stored at c^(r&7); applied inverse on global source
// (linear global_load_lds dest); read offsets are loop-invariant (rA&7 == l15&7).
template <int EPI>
__global__ __launch_bounds__(512, 2) void gemm_bt(const uint16_t* __restrict__ A,
                                                  const uint16_t* __restrict__ B,
                                                  const float* __restrict__ bias,
                                                  void* __restrict__ outp) {
  __shared__ __align__(16) uint16_t lds[8 * 8192];  // 128 KB

  const int tid = threadIdx.x;
  const int nbx = gridDim.x;
  const int nwg = nbx * gridDim.y;
  const int orig = blockIdx.y * nbx + blockIdx.x;
  // bijective XCD swizzle (m204 form)
  const int xcd = orig & 7, rr = nwg & 7, qq = nwg >> 3;
  const int idr = (xcd < rr ? xcd * (qq + 1) : rr * (qq + 1) + (xcd - rr) * qq) + (orig >> 3);
  const int tile_n = (idr % nbx) * 256;
  const int tile_m = (idr / nbx) * 256;

  const int lane = tid & 63;
  const int wave = tid >> 6;
  const int l15 = lane & 15, quad = lane >> 4;
  const int wr = wave >> 2, wc = wave & 3;
  const int wm = wr * 128, wn = wc * 64;

  f32x4 acc[8][4];
#pragma unroll
  for (int mi = 0; mi < 8; mi++)
#pragma unroll
    for (int ni = 0; ni < 4; ni++) acc[mi][ni] = f4zero();

  // per-thread staging geometry (loop-invariant)
  const int st_r = tid >> 3;
  const int st_c = (tid & 7) ^ (st_r & 7);

  auto STAGE = [&](const uint16_t* src, int rowbase, int kt, int slot) {
#pragma unroll
    for (int jj = 0; jj < 2; ++jj) {
      const int row = rowbase + st_r + jj * 64;
      async16(src + (size_t)row * KDIM + kt * 64 + st_c * 8,
              (uint8_t*)(lds + slot * 8192) + tid * 16 + jj * 8192);
    }
  };

  // loop-invariant fragment-read swizzle offsets (rA&7 == rB&7 == l15&7)
  const int sw0 = (quad ^ (l15 & 7)) * 8;
  const int sw1 = ((4 + quad) ^ (l15 & 7)) * 8;
  const uint16_t* Aslot = lds + (size_t)wr * 8192;
  const uint16_t* Bslot = lds + (size_t)(4 + (wc >> 1)) * 8192;
  const int rBb = (wc & 1) * 64;

  // prologue: tile0 A+B, tile1 B; allow tile1's B halves (4 loads) to fly
  STAGE(A, tile_m, 0, 0);
  STAGE(A, tile_m + 128, 0, 1);
  STAGE(B, tile_n, 0, 4);
  STAGE(B, tile_n + 128, 0, 5);
  STAGE(B, tile_n, 1, 6);
  STAGE(B, tile_n + 128, 1, 7);
  asm volatile("s_waitcnt vmcnt(4)" ::: "memory");
  __builtin_amdgcn_s_barrier();

  const int NIT = KDIM / 128;  // 6
  for (int j = 0; j < NIT; ++j) {
    const int S = 2 * j;
    const bool stg = (j < NIT - 1);
#pragma unroll
    for (int pb = 0; pb < 2; ++pb) {
      bf16x8 bfr[4][2];
#pragma unroll
      for (int q = 0; q < 4; ++q) {
        // ---- ds reads for this phase
        if (q == 0) {
#pragma unroll
          for (int ni = 0; ni < 4; ++ni) {
            const int rB = rBb + ni * 16 + l15;
            const uint16_t* bp = Bslot + pb * 16384 + rB * 64;
            bfr[ni][0] = *(const bf16x8*)(bp + sw0);
            bfr[ni][1] = *(const bf16x8*)(bp + sw1);
          }
        }
        bf16x8 af[2][2];
#pragma unroll
        for (int m2 = 0; m2 < 2; ++m2) {
          const int rA = (q * 2 + m2) * 16 + l15;
          const uint16_t* ap = Aslot + pb * 16384 + rA * 64;
          af[m2][0] = *(const bf16x8*)(ap + sw0);
          af[m2][1] = *(const bf16x8*)(ap + sw1);
        }
        // ---- stage one half-tile per schedule
        if (pb == 0) {
          if (q == 0) STAGE(A, tile_m, S + 1, 2);
          else if (q == 1) STAGE(A, tile_m + 128, S + 1, 3);
          else if (q == 2) { if (stg) STAGE(B, tile_n, S + 2, 4); }
          else { if (stg) STAGE(B, tile_n + 128, S + 2, 5); }
        } else {
          if (q == 0) { if (stg) STAGE(A, tile_m, S + 2, 0); }
          else if (q == 1) { if (stg) STAGE(A, tile_m + 128, S + 2, 1); }
          else if (q == 2) { if (stg) STAGE(B, tile_n, S + 3, 6); }
          else { if (stg) STAGE(B, tile_n + 128, S + 3, 7); }
        }
        __builtin_amdgcn_s_barrier();
        asm volatile("s_waitcnt lgkmcnt(0)" ::: "memory");
        __builtin_amdgcn_sched_barrier(0);
        __builtin_amdgcn_s_setprio(1);
#pragma unroll
        for (int kk = 0; kk < 2; ++kk)
#pragma unroll
          for (int m2 = 0; m2 < 2; ++m2)
#pragma unroll
            for (int ni = 0; ni < 4; ++ni)
              acc[q * 2 + m2][ni] = mfma16(af[m2][kk], bfr[ni][kk], acc[q * 2 + m2][ni]);
        __builtin_amdgcn_s_setprio(0);
        if (q == 3) {
          if (stg) asm volatile("s_waitcnt vmcnt(4)" ::: "memory");
          else asm volatile("s_waitcnt vmcnt(0)" ::: "memory");
        }
        __builtin_amdgcn_s_barrier();
      }
    }
  }

#pragma unroll
  for (int mi = 0; mi < 8; mi++) {
#pragma unroll
    for (int ni = 0; ni < 4; ni++) {
#pragma unroll
      for (int rg = 0; rg < 4; rg++) {
        const int m = tile_m + wm + mi * 16 + quad * 4 + rg;
        const int n = tile_n + wn + ni * 16 + l15;
        float v = acc[mi][ni][rg] + bias[n];
        if (EPI == 0) {
          const int which = n / HIDDEN;
          const int rem = n - which * HIDDEN;
          const int head = rem >> 6, d = rem & 63;
          const int b = m / HW;
          const int s = m - b * HW;
          if (which == 0) v *= 0.125f;  // q pre-scaled by hd^-0.5
          ((uint16_t*)outp)[(((size_t)which * BH + (size_t)b * NH + head) * HW + s) * 64 + d] =
              f2bf(v);
        } else {
          ((float*)outp)[(size_t)m * HIDDEN + n] = v;
        }
      }
    }
  }
}

// ---------------- fused attention (swapped-operand form) ----------------
__global__ __launch_bounds__(256, 4) void attn_kernel(const uint16_t* __restrict__ qkv,
                                                      const uint16_t* __restrict__ Rt,
                                                      uint16_t* __restrict__ aout) {
  __shared__ __align__(16) uint8_t smem[37376];
  uint16_t* Ks = (uint16_t*)smem;              // [208][64] chunk-swizzled
  uint16_t* Vt = (uint16_t*)smem;              // [64][224] kappa-order, chunk-swizzled
  uint16_t* Ts = (uint16_t*)(smem + 28672);    // [64][68]: T^T[r][q_local]

  const int wgid = blockIdx.x;                 // 0..12287
  const int jsw = (wgid & 7) * 1536 + (wgid >> 3);  // XCD swizzle (12288 % 8 == 0)
  const int qt = jsw & 3;
  const int bh = jsw >> 2;
  const int q0 = qt * 64;
  const int tid = threadIdx.x;
  const int wave = tid >> 6, lane = tid & 63;
  const int l15 = lane & 15, quad = lane >> 4;

  const uint16_t* qg = qkv + (size_t)bh * HW * 64;
  const uint16_t* kg = qkv + ((size_t)BH + bh) * HW * 64;
  const uint16_t* vg = qkv + ((size_t)2 * BH + bh) * HW * 64;

  // ---- stage K -> Ks, chunk-swizzled: (r, chunk c) at r*64 + (c^(r&7))*8
#pragma unroll
  for (int i = 0; i < 7; i++) {
    const int c = tid + i * 256;
    if (c < 1568) {
      const int r = c >> 3, ch = c & 7;
      uint4 v = *(const uint4*)(kg + (size_t)r * 64 + ch * 8);
      *(uint4*)(Ks + r * 64 + ((ch ^ (r & 7)) * 8)) = v;
    }
  }

  // ---- Q fragment straight from global (b-operand: row=l15, chunk=quad)
  const int qrow = q0 + wave * 16 + l15;       // this lane's q row
  const int qr = (qrow < HW) ? qrow : (HW - 1);
  bf16x8 qb0 = *(const bf16x8*)(qg + (size_t)qr * 64 + quad * 8);
  bf16x8 qb1 = *(const bf16x8*)(qg + (size_t)qr * 64 + 32 + quad * 8);

  // ---- T^T = Rt * Q^T : lane holds T^T[r = t*16+quad*4+rg][q=l15]; spill to Ts
  {
    f32x4 racc[4];
#pragma unroll
    for (int t = 0; t < 4; t++) racc[t] = f4zero();
    __builtin_amdgcn_s_setprio(1);
#pragma unroll
    for (int t = 0; t < 4; t++) {
      bf16x8 r0 = *(const bf16x8*)(Rt + (t * 16 + l15) * 64 + quad * 8);
      bf16x8 r1 = *(const bf16x8*)(Rt + (t * 16 + l15) * 64 + 32 + quad * 8);
      racc[t] = mfma16(r0, qb0, racc[t]);
      racc[t] = mfma16(r1, qb1, racc[t]);
    }
    __builtin_amdgcn_s_setprio(0);
#pragma unroll
    for (int t = 0; t < 4; t++)
#pragma unroll
      for (int rg = 0; rg < 4; rg++)
        Ts[(t * 16 + quad * 4 + rg) * 68 + wave * 16 + l15] = f2bf(racc[t][rg]);
  }

  __syncthreads();  // Ks staged (Ts writes also ordered before all later reads)

  // ---- prefetch V into registers (latency hidden under S-phase MFMAs)
  uint4 vreg[7];
#pragma unroll
  for (int i = 0; i < 7; i++) {
    const int c = tid + i * 256;
    vreg[i] = (c < 1568) ? *(const uint4*)(vg + (size_t)c * 8) : make_uint4(0u, 0u, 0u, 0u);
  }

  // ---- S^T = K * Q^T : lane holds S[j = t*16+quad*4+rg][its own q]
  f32x4 sacc[13];
#pragma unroll
  for (int t = 0; t < 13; t++) sacc[t] = f4zero();
  {
    const int sw0 = (quad ^ (l15 & 7)) * 8;
    const int sw1 = ((quad + 4) ^ (l15 & 7)) * 8;
    __builtin_amdgcn_s_setprio(1);
#pragma unroll
    for (int t = 0; t < 13; t++) {
      const uint16_t* kr = Ks + (t * 16 + l15) * 64;
      bf16x8 a0 = *(const bf16x8*)(kr + sw0);
      bf16x8 a1 = *(const bf16x8*)(kr + sw1);
      sacc[t] = mfma16(a0, qb0, sacc[t]);
      sacc[t] = mfma16(a1, qb1, sacc[t]);
    }
    __builtin_amdgcn_s_setprio(0);
  }

  __syncthreads();  // all waves done reading Ks; V loads drained before overlay

  // ---- zero the kappa-tail columns [196,224) of Vt (one store per thread)
  {
    const int d = tid & 63, wv = tid >> 6;
    if (wv == 0) *(uint2*)(Vt + d * 224 + 196) = make_uint2(0u, 0u);
    else *(uint4*)(Vt + d * 224 + 200 + (wv - 1) * 8) = make_uint4(0u, 0u, 0u, 0u);
  }

  // ---- V^T into Vt in kappa-order, swizzled; writes are bank-conflict-free
  // kappa(j): j = t*16 + qj*4 + rg  ->  (t>>1)*32 + qj*8 + (t&1)*4 + rg
#pragma unroll
  for (int i = 0; i < 7; i++) {
    const int c = tid + i * 256;
    if (c < 1568) {
      const int jj = c >> 3;
      const int dp = c & 7;               // d block: rows dp*8 .. dp*8+7
      const int tt = jj >> 4;
      const int kap = (tt >> 1) * 32 + ((jj >> 2) & 3) * 8 + (tt & 1) * 4 + (jj & 3);
      const int cj = kap >> 3;
      const int chs = (cj < 24) ? ((cj & 24) | ((cj & 7) ^ dp)) : cj;
      uint16_t* dst = Vt + dp * 8 * 224 + chs * 8 + (kap & 7);
      const uint16_t* pe = (const uint16_t*)&vreg[i];
#pragma unroll
      for (int e = 0; e < 8; e++) dst[e * 224] = pe[e];
    }
  }

  // ---- softmax fully in registers (row = lane's own q); bias from Ts
  uint32_t P2[13][2];
  {
    const int hq = (qr * 586) >> 13;      // qr / 14
    const int wq = qr - hq * 14;
    const uint16_t* Tb = Ts + wave * 16 + l15;   // column base, rows stride 68
    const int c0 = (hq + 13) * 68;
    const int c1 = (wq + 45) * 68;
    float mx0 = -1e30f, mx1 = -1e30f, mx2 = -1e30f, mx3 = -1e30f;
#pragma unroll
    for (int t = 0; t < 13; t++) {
#pragma unroll
      for (int rg = 0; rg < 4; rg++) {
        const int j = t * 16 + quad * 4 + rg;
        const int kh = (j * 586) >> 13;   // j / 14 (valid for j <= 195)
        const int kw = j - kh * 14;
        const float b = bf2f(Tb[c0 - kh * 68]) + bf2f(Tb[c1 - kw * 68]);
        float s = sacc[t][rg] + b;
        s = (j < HW) ? s : -1e30f;
        sacc[t][rg] = s;
        if (rg == 0) mx0 = fmaxf(mx0, s);
        else if (rg == 1) mx1 = fmaxf(mx1, s);
        else if (rg == 2) mx2 = fmaxf(mx2, s);
        else mx3 = fmaxf(mx3, s);
      }
    }
    float mx = fmaxf(fmaxf(mx0, mx1), fmaxf(mx2, mx3));
    mx = fmaxf(mx, __shfl_xor(mx, 16, 64));
    mx = fmaxf(mx, __shfl_xor(mx, 32, 64));
    float s0 = 0.f, s1 = 0.f, s2 = 0.f, s3 = 0.f;
#pragma unroll
    for (int t = 0; t < 13; t++) {
#pragma unroll
      for (int rg = 0; rg < 4; rg++) {
        const float p = __expf(sacc[t][rg] - mx);
        sacc[t][rg] = p;
        if (rg == 0) s0 += p;
        else if (rg == 1) s1 += p;
        else if (rg == 2) s2 += p;
        else s3 += p;
      }
    }
    float sum = (s0 + s1) + (s2 + s3);
    sum += __shfl_xor(sum, 16, 64);
    sum += __shfl_xor(sum, 32, 64);
    const float inv = 1.f / sum;
#pragma unroll
    for (int t = 0; t < 13; t++) {
      P2[t][0] = pack2bf(sacc[t][0] * inv, sacc[t][1] * inv);
      P2[t][1] = pack2bf(sacc[t][2] * inv, sacc[t][3] * inv);
    }
  }

  __syncthreads();  // all Vt writes visible before PV reads

  // ---- O = P*V : A-fragment is the lane's own P2 registers (kappa order)
  f32x4 oacc[4];
#pragma unroll
  for (int nt = 0; nt < 4; nt++) oacc[nt] = f4zero();
  {
    __builtin_amdgcn_s_setprio(1);
#pragma unroll
    for (int ks = 0; ks < 7; ks++) {
      uint4 aw;
      aw.x = P2[2 * ks][0];
      aw.y = P2[2 * ks][1];
      aw.z = (ks < 6) ? P2[2 * ks + 1][0] : 0u;
      aw.w = (ks < 6) ? P2[2 * ks + 1][1] : 0u;
      const bf16x8 af = __builtin_bit_cast(bf16x8, aw);
      const int cb = ks * 4 + quad;       // kappa chunk
#pragma unroll
      for (int nt = 0; nt < 4; nt++) {
        const int d = nt * 16 + l15;
        const int p = (d >> 3) & 7;
        const int chs = (cb < 24) ? ((cb & 24) | ((cb & 7) ^ p)) : cb;
        bf16x8 bv = *(const bf16x8*)(Vt + d * 224 + chs * 8);
        oacc[nt] = mfma16(af, bv, oacc[nt]);
      }
    }
    __builtin_amdgcn_s_setprio(0);
  }

  const int b = bh / NH, head = bh - b * NH;
#pragma unroll
  for (int nt = 0; nt < 4; nt++) {
#pragma unroll
    for (int rg = 0; rg < 4; rg++) {
      const int qro = q0 + wave * 16 + quad * 4 + rg;
      if (qro < HW) {
        const int d = nt * 16 + l15;
        aout[((size_t)b * HW + qro) * HIDDEN + head * 64 + d] = f2bf(oacc[nt][rg]);
      }
    }
  }
}

extern "C" void kernel_launch(void* const* d_in, const int* in_sizes, int n_in,
                              void* d_out, int out_size, void* d_ws, size_t ws_size,
                              hipStream_t stream) {
  const float* hidden = (const float*)d_in[0];
  const float* qkv_w = (const float*)d_in[1];
  const float* qkv_b = (const float*)d_in[2];
  const float* proj_w = (const float*)d_in[3];
  const float* proj_b = (const float*)d_in[4];
  const float* rel_h = (const float*)d_in[5];
  const float* rel_w = (const float*)d_in[6];

  uint8_t* ws = (uint8_t*)d_ws;
  uint16_t* Xb = (uint16_t*)(ws);                  // 77,070,336 B; reused as attn_out
  uint16_t* qkvb = (uint16_t*)(ws + 77070336);     // 231,211,008 B: [3][3072][196][64] bf16
  uint16_t* Rt = (uint16_t*)(ws + 308281344);      // 8,192 B: [64][64] bf16 rel table
  uint16_t* wqkvb = (uint16_t*)(ws + 308289536);   // 3,538,944 B
  uint16_t* wprjb = (uint16_t*)(ws + 311828480);   // 1,179,648 B

  prep<<<5712, 256, 0, stream>>>(hidden, qkv_w, proj_w, rel_h, rel_w,
                                 Xb, wqkvb, wprjb, Rt);

  gemm_bt<0><<<dim3(9, 196), 512, 0, stream>>>(Xb, wqkvb, qkv_b, (void*)qkvb);
  attn_kernel<<<dim3(12288), 256, 0, stream>>>(qkvb, Rt, Xb);
  gemm_bt<1><<<dim3(3, 196), 512, 0, stream>>>(Xb, wprjb, proj_b, d_out);
}

// Round 8
// 701.494 us; speedup vs baseline: 1.0606x; 1.0099x over previous
//
#include <hip/hip_runtime.h>
#include <stdint.h>

#define WIN 14
#define HW 196
#define NH 12
#define HIDDEN 768
#define BH 3072
#define MTOT 50176
#define KDIM 768

typedef __bf16 bf16x8 __attribute__((ext_vector_type(8)));
typedef float f32x4 __attribute__((ext_vector_type(4)));

__device__ __forceinline__ float bf2f(uint16_t u) {
  union { uint32_t i; float f; } v; v.i = ((uint32_t)u) << 16; return v.f;
}
__device__ __forceinline__ uint16_t f2bf(float f) {
  uint32_t u = __float_as_uint(f);
  uint32_t r = u + 0x7FFFu + ((u >> 16) & 1u);
  return (uint16_t)(r >> 16);
}
__device__ __forceinline__ uint32_t pack2bf(float a, float b) {
  return (uint32_t)f2bf(a) | ((uint32_t)f2bf(b) << 16);
}
__device__ __forceinline__ f32x4 mfma16(bf16x8 a, bf16x8 b, f32x4 c) {
  return __builtin_amdgcn_mfma_f32_16x16x32_bf16(a, b, c, 0, 0, 0);
}
__device__ __forceinline__ f32x4 f4zero() { f32x4 z = {0.f, 0.f, 0.f, 0.f}; return z; }

__device__ __forceinline__ void async16(const void* g, void* l) {
#if __has_builtin(__builtin_amdgcn_global_load_lds)
  __builtin_amdgcn_global_load_lds((__attribute__((address_space(1))) void*)g,
                                   (__attribute__((address_space(3))) void*)l, 16, 0, 0);
#else
  *(uint4*)l = *(const uint4*)g;
#endif
}

// ---------------- fused prep: 3x fp32->bf16 convert + rel-pos table ----------------
// blocks [0,4096): hidden; [4096,5120): qkv_w; [5120,5696): proj_w; [5696,5712): Rt.
__global__ __launch_bounds__(256) void prep(const float* __restrict__ hidden,
                                            const float* __restrict__ qkv_w,
                                            const float* __restrict__ proj_w,
                                            const float* __restrict__ rh,
                                            const float* __restrict__ rw,
                                            uint16_t* __restrict__ Xb,
                                            uint16_t* __restrict__ wqkvb,
                                            uint16_t* __restrict__ wprjb,
                                            uint16_t* __restrict__ Rt) {
  const int blk = blockIdx.x;
  if (blk < 4096) {
    const int n4 = (MTOT * HIDDEN) / 4;
    int i = blk * 256 + threadIdx.x;
    for (; i < n4; i += 4096 * 256) {
      float4 v = ((const float4*)hidden)[i];
      ushort4 o;
      o.x = f2bf(v.x); o.y = f2bf(v.y); o.z = f2bf(v.z); o.w = f2bf(v.w);
      ((ushort4*)Xb)[i] = o;
    }
  } else if (blk < 5120) {
    const int n4 = (3 * HIDDEN * HIDDEN) / 4;
    int i = (blk - 4096) * 256 + threadIdx.x;
    for (; i < n4; i += 1024 * 256) {
      float4 v = ((const float4*)qkv_w)[i];
      ushort4 o;
      o.x = f2bf(v.x); o.y = f2bf(v.y); o.z = f2bf(v.z); o.w = f2bf(v.w);
      ((ushort4*)wqkvb)[i] = o;
    }
  } else if (blk < 5696) {
    const int n4 = (HIDDEN * HIDDEN) / 4;
    int i = (blk - 5120) * 256 + threadIdx.x;
    if (i < n4) {
      float4 v = ((const float4*)proj_w)[i];
      ushort4 o;
      o.x = f2bf(v.x); o.y = f2bf(v.y); o.z = f2bf(v.z); o.w = f2bf(v.w);
      ((ushort4*)wprjb)[i] = o;
    }
  } else {
    const int i = (blk - 5696) * 256 + threadIdx.x;
    if (i < 4096) {
      const int r = i >> 6, c = i & 63;
      float v = 0.f;
      if (r < 27) v = rh[r * 64 + c] * 8.f;
      else if (r >= 32 && r < 59) v = rw[(r - 32) * 64 + c] * 8.f;
      Rt[i] = f2bf(v);
    }
  }
}

// ---------------- GEMM: C[m][n] = sum_k A[m][k]*B[n][k] (+bias), bf16 in, K=768 ----
// R3-exact (best measured: 206 us, WRITE clean). 256x256 tile, BK=64, 8 waves,
// 8-phase double-barrier schedule (T3+T4+T5). 128 KB LDS, counted vmcnt(4).
template <int EPI>
__global__ __launch_bounds__(512, 2) void gemm_bt(const uint16_t* __restrict__ A,
                                                  const uint16_t* __restrict__ B,
                                                  const float* __restrict__ bias,
                                                  void* __restrict__ outp) {
  __shared__ __align__(16) uint16_t lds[8 * 8192];  // 128 KB

  const int tid = threadIdx.x;
  const int nbx = gridDim.x;
  const int nwg = nbx * gridDim.y;
  const int orig = blockIdx.y * nbx + blockIdx.x;
  // bijective XCD swizzle (m204 form)
  const int xcd = orig & 7, rr = nwg & 7, qq = nwg >> 3;
  const int idr = (xcd < rr ? xcd * (qq + 1) : rr * (qq + 1) + (xcd - rr) * qq) + (orig >> 3);
  const int tile_n = (idr % nbx) * 256;
  const int tile_m = (idr / nbx) * 256;

  const int lane = tid & 63;
  const int wave = tid >> 6;
  const int l15 = lane & 15, quad = lane >> 4;
  const int wr = wave >> 2, wc = wave & 3;
  const int wm = wr * 128, wn = wc * 64;

  f32x4 acc[8][4];
#pragma unroll
  for (int mi = 0; mi < 8; mi++)
#pragma unroll
    for (int ni = 0; ni < 4; ni++) acc[mi][ni] = f4zero();

  // per-thread staging geometry (loop-invariant)
  const int st_r = tid >> 3;
  const int st_c = (tid & 7) ^ (st_r & 7);

  auto STAGE = [&](const uint16_t* src, int rowbase, int kt, int slot) {
#pragma unroll
    for (int jj = 0; jj < 2; ++jj) {
      const int row = rowbase + st_r + jj * 64;
      async16(src + (size_t)row * KDIM + kt * 64 + st_c * 8,
              (uint8_t*)(lds + slot * 8192) + tid * 16 + jj * 8192);
    }
  };

  // loop-invariant fragment-read swizzle offsets (rA&7 == rB&7 == l15&7)
  const int sw0 = (quad ^ (l15 & 7)) * 8;
  const int sw1 = ((4 + quad) ^ (l15 & 7)) * 8;
  const uint16_t* Aslot = lds + (size_t)wr * 8192;
  const uint16_t* Bslot = lds + (size_t)(4 + (wc >> 1)) * 8192;
  const int rBb = (wc & 1) * 64;

  // prologue: tile0 A+B, tile1 B; allow tile1's B halves (4 loads) to fly
  STAGE(A, tile_m, 0, 0);
  STAGE(A, tile_m + 128, 0, 1);
  STAGE(B, tile_n, 0, 4);
  STAGE(B, tile_n + 128, 0, 5);
  STAGE(B, tile_n, 1, 6);
  STAGE(B, tile_n + 128, 1, 7);
  asm volatile("s_waitcnt vmcnt(4)" ::: "memory");
  __builtin_amdgcn_s_barrier();

  const int NIT = KDIM / 128;  // 6
  for (int j = 0; j < NIT; ++j) {
    const int S = 2 * j;
    const bool stg = (j < NIT - 1);
#pragma unroll
    for (int pb = 0; pb < 2; ++pb) {
      bf16x8 bfr[4][2];
#pragma unroll
      for (int q = 0; q < 4; ++q) {
        // ---- ds reads for this phase
        if (q == 0) {
#pragma unroll
          for (int ni = 0; ni < 4; ++ni) {
            const int rB = rBb + ni * 16 + l15;
            const uint16_t* bp = Bslot + pb * 16384 + rB * 64;
            bfr[ni][0] = *(const bf16x8*)(bp + sw0);
            bfr[ni][1] = *(const bf16x8*)(bp + sw1);
          }
        }
        bf16x8 af[2][2];
#pragma unroll
        for (int m2 = 0; m2 < 2; ++m2) {
          const int rA = (q * 2 + m2) * 16 + l15;
          const uint16_t* ap = Aslot + pb * 16384 + rA * 64;
          af[m2][0] = *(const bf16x8*)(ap + sw0);
          af[m2][1] = *(const bf16x8*)(ap + sw1);
        }
        // ---- stage one half-tile per schedule
        if (pb == 0) {
          if (q == 0) STAGE(A, tile_m, S + 1, 2);
          else if (q == 1) STAGE(A, tile_m + 128, S + 1, 3);
          else if (q == 2) { if (stg) STAGE(B, tile_n, S + 2, 4); }
          else { if (stg) STAGE(B, tile_n + 128, S + 2, 5); }
        } else {
          if (q == 0) { if (stg) STAGE(A, tile_m, S + 2, 0); }
          else if (q == 1) { if (stg) STAGE(A, tile_m + 128, S + 2, 1); }
          else if (q == 2) { if (stg) STAGE(B, tile_n, S + 3, 6); }
          else { if (stg) STAGE(B, tile_n + 128, S + 3, 7); }
        }
        __builtin_amdgcn_s_barrier();
        asm volatile("s_waitcnt lgkmcnt(0)" ::: "memory");
        __builtin_amdgcn_sched_barrier(0);
        __builtin_amdgcn_s_setprio(1);
#pragma unroll
        for (int kk = 0; kk < 2; ++kk)
#pragma unroll
          for (int m2 = 0; m2 < 2; ++m2)
#pragma unroll
            for (int ni = 0; ni < 4; ++ni)
              acc[q * 2 + m2][ni] = mfma16(af[m2][kk], bfr[ni][kk], acc[q * 2 + m2][ni]);
        __builtin_amdgcn_s_setprio(0);
        if (q == 3) {
          if (stg) asm volatile("s_waitcnt vmcnt(4)" ::: "memory");
          else asm volatile("s_waitcnt vmcnt(0)" ::: "memory");
        }
        __builtin_amdgcn_s_barrier();
      }
    }
  }

#pragma unroll
  for (int mi = 0; mi < 8; mi++) {
#pragma unroll
    for (int ni = 0; ni < 4; ni++) {
#pragma unroll
      for (int rg = 0; rg < 4; rg++) {
        const int m = tile_m + wm + mi * 16 + quad * 4 + rg;
        const int n = tile_n + wn + ni * 16 + l15;
        float v = acc[mi][ni][rg] + bias[n];
        if (EPI == 0) {
          const int which = n / HIDDEN;
          const int rem = n - which * HIDDEN;
          const int head = rem >> 6, d = rem & 63;
          const int b = m / HW;
          const int s = m - b * HW;
          if (which == 0) v *= 0.125f;  // q pre-scaled by hd^-0.5
          ((uint16_t*)outp)[(((size_t)which * BH + (size_t)b * NH + head) * HW + s) * 64 + d] =
              f2bf(v);
        } else {
          ((float*)outp)[(size_t)m * HIDDEN + n] = v;
        }
      }
    }
  }
}

// ---------------- fused attention (swapped-operand form) ----------------
// ACTIVE-WAVE SKIP: 196 rows need only 13 of the 16 allocated 16-row groups;
// waves whose whole group is >= HW (3 waves of every qt=3 block, 18.75% of all
// wave-compute) skip T/S/softmax/PV entirely (wave-uniform branch, no barriers
// inside). They still do K-staging, V prefetch/scatter, and hit all barriers.
__global__ __launch_bounds__(256, 4) void attn_kernel(const uint16_t* __restrict__ qkv,
                                                      const uint16_t* __restrict__ Rt,
                                                      uint16_t* __restrict__ aout) {
  __shared__ __align__(16) uint8_t smem[37376];
  uint16_t* Ks = (uint16_t*)smem;              // [208][64] chunk-swizzled
  uint16_t* Vt = (uint16_t*)smem;              // [64][224] kappa-order, chunk-swizzled
  uint16_t* Ts = (uint16_t*)(smem + 28672);    // [64][68]: T^T[r][q_local]

  const int wgid = blockIdx.x;                 // 0..12287
  const int jsw = (wgid & 7) * 1536 + (wgid >> 3);  // XCD swizzle (12288 % 8 == 0)
  const int qt = jsw & 3;
  const int bh = jsw >> 2;
  const int q0 = qt * 64;
  const int tid = threadIdx.x;
  const int wave = tid >> 6, lane = tid & 63;
  const int l15 = lane & 15, quad = lane >> 4;
  const bool active = (q0 + wave * 16) < HW;   // wave-uniform

  const uint16_t* qg = qkv + (size_t)bh * HW * 64;
  const uint16_t* kg = qkv + ((size_t)BH + bh) * HW * 64;
  const uint16_t* vg = qkv + ((size_t)2 * BH + bh) * HW * 64;

  // ---- stage K -> Ks, chunk-swizzled: (r, chunk c) at r*64 + (c^(r&7))*8
#pragma unroll
  for (int i = 0; i < 7; i++) {
    const int c = tid + i * 256;
    if (c < 1568) {
      const int r = c >> 3, ch = c & 7;
      uint4 v = *(const uint4*)(kg + (size_t)r * 64 + ch * 8);
      *(uint4*)(Ks + r * 64 + ((ch ^ (r & 7)) * 8)) = v;
    }
  }

  // ---- Q fragment straight from global (b-operand: row=l15, chunk=quad)
  const int qrow = q0 + wave * 16 + l15;       // this lane's q row
  const int qr = (qrow < HW) ? qrow : (HW - 1);
  bf16x8 qb0, qb1;
  {
    uint4 z = make_uint4(0u, 0u, 0u, 0u);
    qb0 = __builtin_bit_cast(bf16x8, z);
    qb1 = __builtin_bit_cast(bf16x8, z);
  }
  if (active) {
    qb0 = *(const bf16x8*)(qg + (size_t)qr * 64 + quad * 8);
    qb1 = *(const bf16x8*)(qg + (size_t)qr * 64 + 32 + quad * 8);
  }

  // ---- T^T = Rt * Q^T : lane holds T^T[r = t*16+quad*4+rg][q=l15]; spill to Ts
  if (active) {
    f32x4 racc[4];
#pragma unroll
    for (int t = 0; t < 4; t++) racc[t] = f4zero();
    __builtin_amdgcn_s_setprio(1);
#pragma unroll
    for (int t = 0; t < 4; t++) {
      bf16x8 r0 = *(const bf16x8*)(Rt + (t * 16 + l15) * 64 + quad * 8);
      bf16x8 r1 = *(const bf16x8*)(Rt + (t * 16 + l15) * 64 + 32 + quad * 8);
      racc[t] = mfma16(r0, qb0, racc[t]);
      racc[t] = mfma16(r1, qb1, racc[t]);
    }
    __builtin_amdgcn_s_setprio(0);
#pragma unroll
    for (int t = 0; t < 4; t++)
#pragma unroll
      for (int rg = 0; rg < 4; rg++)
        Ts[(t * 16 + quad * 4 + rg) * 68 + wave * 16 + l15] = f2bf(racc[t][rg]);
  }

  __syncthreads();  // Ks staged (Ts writes also ordered before all later reads)

  // ---- prefetch V into registers (latency hidden under S-phase MFMAs)
  uint4 vreg[7];
#pragma unroll
  for (int i = 0; i < 7; i++) {
    const int c = tid + i * 256;
    vreg[i] = (c < 1568) ? *(const uint4*)(vg + (size_t)c * 8) : make_uint4(0u, 0u, 0u, 0u);
  }

  // ---- S^T = K * Q^T : lane holds S[j = t*16+quad*4+rg][its own q]
  f32x4 sacc[13];
#pragma unroll
  for (int t = 0; t < 13; t++) sacc[t] = f4zero();
  if (active) {
    const int sw0 = (quad ^ (l15 & 7)) * 8;
    const int sw1 = ((quad + 4) ^ (l15 & 7)) * 8;
    __builtin_amdgcn_s_setprio(1);
#pragma unroll
    for (int t = 0; t < 13; t++) {
      const uint16_t* kr = Ks + (t * 16 + l15) * 64;
      bf16x8 a0 = *(const bf16x8*)(kr + sw0);
      bf16x8 a1 = *(const bf16x8*)(kr + sw1);
      sacc[t] = mfma16(a0, qb0, sacc[t]);
      sacc[t] = mfma16(a1, qb1, sacc[t]);
    }
    __builtin_amdgcn_s_setprio(0);
  }

  __syncthreads();  // all waves done reading Ks; V loads drained before overlay

  // ---- zero the kappa-tail columns [196,224) of Vt (one store per thread)
  {
    const int d = tid & 63, wv = tid >> 6;
    if (wv == 0) *(uint2*)(Vt + d * 224 + 196) = make_uint2(0u, 0u);
    else *(uint4*)(Vt + d * 224 + 200 + (wv - 1) * 8) = make_uint4(0u, 0u, 0u, 0u);
  }

  // ---- V^T into Vt in kappa-order, swizzled; writes are bank-conflict-free
  // kappa(j): j = t*16 + qj*4 + rg  ->  (t>>1)*32 + qj*8 + (t&1)*4 + rg
#pragma unroll
  for (int i = 0; i < 7; i++) {
    const int c = tid + i * 256;
    if (c < 1568) {
      const int jj = c >> 3;
      const int dp = c & 7;               // d block: rows dp*8 .. dp*8+7
      const int tt = jj >> 4;
      const int kap = (tt >> 1) * 32 + ((jj >> 2) & 3) * 8 + (tt & 1) * 4 + (jj & 3);
      const int cj = kap >> 3;
      const int chs = (cj < 24) ? ((cj & 24) | ((cj & 7) ^ dp)) : cj;
      uint16_t* dst = Vt + dp * 8 * 224 + chs * 8 + (kap & 7);
      const uint16_t* pe = (const uint16_t*)&vreg[i];
#pragma unroll
      for (int e = 0; e < 8; e++) dst[e * 224] = pe[e];
    }
  }

  // ---- softmax fully in registers (row = lane's own q); bias from Ts
  uint32_t P2[13][2];
  if (active) {
    const int hq = (qr * 586) >> 13;      // qr / 14
    const int wq = qr - hq * 14;
    const uint16_t* Tb = Ts + wave * 16 + l15;   // column base, rows stride 68
    const int c0 = (hq + 13) * 68;
    const int c1 = (wq + 45) * 68;
    float mx0 = -1e30f, mx1 = -1e30f, mx2 = -1e30f, mx3 = -1e30f;
#pragma unroll
    for (int t = 0; t < 13; t++) {
#pragma unroll
      for (int rg = 0; rg < 4; rg++) {
        const int j = t * 16 + quad * 4 + rg;
        const int kh = (j * 586) >> 13;   // j / 14 (valid for j <= 195)
        const int kw = j - kh * 14;
        const float b = bf2f(Tb[c0 - kh * 68]) + bf2f(Tb[c1 - kw * 68]);
        float s = sacc[t][rg] + b;
        s = (j < HW) ? s : -1e30f;
        sacc[t][rg] = s;
        if (rg == 0) mx0 = fmaxf(mx0, s);
        else if (rg == 1) mx1 = fmaxf(mx1, s);
        else if (rg == 2) mx2 = fmaxf(mx2, s);
        else mx3 = fmaxf(mx3, s);
      }
    }
    float mx = fmaxf(fmaxf(mx0, mx1), fmaxf(mx2, mx3));
    mx = fmaxf(mx, __shfl_xor(mx, 16, 64));
    mx = fmaxf(mx, __shfl_xor(mx, 32, 64));
    float s0 = 0.f, s1 = 0.f, s2 = 0.f, s3 = 0.f;
#pragma unroll
    for (int t = 0; t < 13; t++) {
#pragma unroll
      for (int rg = 0; rg < 4; rg++) {
        const float p = __expf(sacc[t][rg] - mx);
        sacc[t][rg] = p;
        if (rg == 0) s0 += p;
        else if (rg == 1) s1 += p;
        else if (rg == 2) s2 += p;
        else s3 += p;
      }
    }
    float sum = (s0 + s1) + (s2 + s3);
    sum += __shfl_xor(sum, 16, 64);
    sum += __shfl_xor(sum, 32, 64);
    const float inv = 1.f / sum;
#pragma unroll
    for (int t = 0; t < 13; t++) {
      P2[t][0] = pack2bf(sacc[t][0] * inv, sacc[t][1] * inv);
      P2[t][1] = pack2bf(sacc[t][2] * inv, sacc[t][3] * inv);
    }
  }

  __syncthreads();  // all Vt writes visible before PV reads

  // ---- O = P*V : A-fragment is the lane's own P2 registers (kappa order)
  if (active) {
    f32x4 oacc[4];
#pragma unroll
    for (int nt = 0; nt < 4; nt++) oacc[nt] = f4zero();
    __builtin_amdgcn_s_setprio(1);
#pragma unroll
    for (int ks = 0; ks < 7; ks++) {
      uint4 aw;
      aw.x = P2[2 * ks][0];
      aw.y = P2[2 * ks][1];
      aw.z = (ks < 6) ? P2[2 * ks + 1][0] : 0u;
      aw.w = (ks < 6) ? P2[2 * ks + 1][1] : 0u;
      const bf16x8 af = __builtin_bit_cast(bf16x8, aw);
      const int cb = ks * 4 + quad;       // kappa chunk
#pragma unroll
      for (int nt = 0; nt < 4; nt++) {
        const int d = nt * 16 + l15;
        const int p = (d >> 3) & 7;
        const int chs = (cb < 24) ? ((cb & 24) | ((cb & 7) ^ p)) : cb;
        bf16x8 bv = *(const bf16x8*)(Vt + d * 224 + chs * 8);
        oacc[nt] = mfma16(af, bv, oacc[nt]);
      }
    }
    __builtin_amdgcn_s_setprio(0);

    const int b = bh / NH, head = bh - b * NH;
#pragma unroll
    for (int nt = 0; nt < 4; nt++) {
#pragma unroll
      for (int rg = 0; rg < 4; rg++) {
        const int qro = q0 + wave * 16 + quad * 4 + rg;
        if (qro < HW) {
          const int d = nt * 16 + l15;
          aout[((size_t)b * HW + qro) * HIDDEN + head * 64 + d] = f2bf(oacc[nt][rg]);
        }
      }
    }
  }
}

extern "C" void kernel_launch(void* const* d_in, const int* in_sizes, int n_in,
                              void* d_out, int out_size, void* d_ws, size_t ws_size,
                              hipStream_t stream) {
  const float* hidden = (const float*)d_in[0];
  const float* qkv_w = (const float*)d_in[1];
  const float* qkv_b = (const float*)d_in[2];
  const float* proj_w = (const float*)d_in[3];
  const float* proj_b = (const float*)d_in[4];
  const float* rel_h = (const float*)d_in[5];
  const float* rel_w = (const float*)d_in[6];

  uint8_t* ws = (uint8_t*)d_ws;
  uint16_t* Xb = (uint16_t*)(ws);                  // 77,070,336 B; reused as attn_out
  uint16_t* qkvb = (uint16_t*)(ws + 77070336);     // 231,211,008 B: [3][3072][196][64] bf16
  uint16_t* Rt = (uint16_t*)(ws + 308281344);      // 8,192 B: [64][64] bf16 rel table
  uint16_t* wqkvb = (uint16_t*)(ws + 308289536);   // 3,538,944 B
  uint16_t* wprjb = (uint16_t*)(ws + 311828480);   // 1,179,648 B

  prep<<<5712, 256, 0, stream>>>(hidden, qkv_w, proj_w, rel_h, rel_w,
                                 Xb, wqkvb, wprjb, Rt);

  gemm_bt<0><<<dim3(9, 196), 512, 0, stream>>>(Xb, wqkvb, qkv_b, (void*)qkvb);
  attn_kernel<<<dim3(12288), 256, 0, stream>>>(qkvb, Rt, Xb);
  gemm_bt<1><<<dim3(3, 196), 512, 0, stream>>>(Xb, wprjb, proj_b, d_out);
}